// Round 5
// baseline (6667.291 us; speedup 1.0000x reference)
//
#include <hip/hip_runtime.h>
#include <math.h>

// ---------------- constants ----------------
// E=1024, T=12, CPT=4, D=64, NH=4, HD=16, FF=256, L=2
// 256 spatial cells (blocks); per cell 256 sequences of (T=12, D=64).
// Phase 3: lane = (sl, t): sl = sub-sequence slot 0..4 (5 seqs/wave), t = 0..11.
// 8 waves x 5 seqs = 40 seqs per pass, 7 passes cover 256.
//
// R4 change: R1 (__launch_bounds__(512,2)) and R2 (amdgpu_waves_per_eu(2,2))
// both left VGPR_Count=128 with 4.2GB spill WRITE_SIZE. 128 = 512/4 waves/EU,
// consistent with launch_bounds arg2 being read CUDA-style (min blocks/CU:
// 2 blocks x 8 waves = 4 waves/EU). LDS=120KB forces 1 block/CU = 2 waves/EU
// regardless, so a 256-reg budget is free. Request it two ways:
//   __launch_bounds__(512, 1)  (>=256 regs under either arg2 semantics)
//   __attribute__((amdgpu_num_vgpr(256)))  (direct allocator budget)

#define LGKM0 asm volatile("s_waitcnt lgkmcnt(0)" ::: "memory")

// 4-output-row matmul quad: A0..A3 = bias[R..R+3] + W[R..R+3][:] . SRC[0:64]
#define QUAD_MM(WROW, BPTR, R, A0, A1, A2, A3, SRC)                         \
  {                                                                         \
    const float* _w = (WROW);                                               \
    A0 = (BPTR)[(R)];                                                       \
    A1 = (BPTR)[(R) + 1];                                                   \
    A2 = (BPTR)[(R) + 2];                                                   \
    A3 = (BPTR)[(R) + 3];                                                   \
    _Pragma("unroll") for (int _d = 0; _d < 64; ++_d) {                     \
      float _hv = SRC[_d];                                                  \
      A0 = fmaf(_w[_d], _hv, A0);                                           \
      A1 = fmaf(_w[64 + _d], _hv, A1);                                      \
      A2 = fmaf(_w[128 + _d], _hv, A2);                                     \
      A3 = fmaf(_w[192 + _d], _hv, A3);                                     \
    }                                                                       \
  }

#define LAYERNORM(GP, BP)                                                   \
  {                                                                         \
    float s1[32];                                                           \
    _Pragma("unroll") for (int i = 0; i < 32; ++i)                          \
        s1[i] = h[2 * i] + h[2 * i + 1];                                    \
    _Pragma("unroll") for (int i = 0; i < 16; ++i) s1[i] += s1[i + 16];     \
    _Pragma("unroll") for (int i = 0; i < 8; ++i) s1[i] += s1[i + 8];       \
    _Pragma("unroll") for (int i = 0; i < 4; ++i) s1[i] += s1[i + 4];       \
    float m_ = (s1[0] + s1[1] + s1[2] + s1[3]) * (1.f / 64.f);              \
    float q1[32];                                                           \
    _Pragma("unroll") for (int i = 0; i < 32; ++i) {                        \
      float d0_ = h[2 * i] - m_, d1_ = h[2 * i + 1] - m_;                   \
      q1[i] = fmaf(d0_, d0_, d1_ * d1_);                                    \
    }                                                                       \
    _Pragma("unroll") for (int i = 0; i < 16; ++i) q1[i] += q1[i + 16];     \
    _Pragma("unroll") for (int i = 0; i < 8; ++i) q1[i] += q1[i + 8];       \
    _Pragma("unroll") for (int i = 0; i < 4; ++i) q1[i] += q1[i + 4];       \
    float v_ = (q1[0] + q1[1] + q1[2] + q1[3]) * (1.f / 64.f);              \
    float rs_ = rsqrtf(v_ + 1e-5f);                                         \
    _Pragma("unroll") for (int d = 0; d < 64; ++d)                          \
        h[d] = fmaf((h[d] - m_) * rs_, (GP)[d], (BP)[d]);                   \
  }

__global__ __launch_bounds__(512, 1)
__attribute__((amdgpu_num_vgpr(256)))
void prithvi_fused(
    const float* __restrict__ x,     const float* __restrict__ conv_w,
    const float* __restrict__ bn_g,  const float* __restrict__ bn_b,
    const float* __restrict__ bn_m,  const float* __restrict__ bn_v,
    const float* __restrict__ w_in,  const float* __restrict__ qkv_w,
    const float* __restrict__ qkv_b, const float* __restrict__ ow,
    const float* __restrict__ ob,    const float* __restrict__ ln1_g,
    const float* __restrict__ ln1_b, const float* __restrict__ ff1_w,
    const float* __restrict__ ff1_b, const float* __restrict__ ff2_w,
    const float* __restrict__ ff2_b, const float* __restrict__ ln2_g,
    const float* __restrict__ ln2_b, const float* __restrict__ w_out,
    const float* __restrict__ b_out, float* __restrict__ out)
{
  // sbuf: phase1 = x-slice transposed [t][e] (12x1024); phase2 output g [o][t] (1024x12)
  __shared__ __align__(16) float sbuf[12288];              // 48 KB
  // per-wave row buffer: 64 rows x 36 words (rows: row = t*5+sl)
  __shared__ __align__(16) float Tbuf[8 * 64 * 36];        // 72 KB

  const int sp   = blockIdx.x;    // hp*16 + wp
  const int tid  = threadIdx.x;
  const int lane = tid & 63;
  const int wave = tid >> 6;

  // ---------------- phase 1: stage x slice transposed: sbuf[t*1024+e] ----------------
  for (int ch = tid; ch < 12288; ch += 512) {
    int e = ch / 12;
    int t = ch - e * 12;
    sbuf[t * 1024 + e] = x[(size_t)ch * 256 + sp];
  }
  __syncthreads();

  // ---------------- phase 2: 1x1 conv (acc in regs) ----------------
  float acc0[12], acc1[12];
#pragma unroll
  for (int t = 0; t < 12; ++t) { acc0[t] = 0.f; acc1[t] = 0.f; }
  {
    const float* w0p = conv_w + tid * 1024;
    const float* w1p = conv_w + (tid + 512) * 1024;
    for (int eb = 0; eb < 1024; eb += 4) {
      float4 wa = *(const float4*)(w0p + eb);
      float4 wb = *(const float4*)(w1p + eb);
#pragma unroll
      for (int t = 0; t < 12; ++t) {
        float4 xv = *(const float4*)&sbuf[t * 1024 + eb];
        acc0[t] = fmaf(xv.x, wa.x, acc0[t]);
        acc0[t] = fmaf(xv.y, wa.y, acc0[t]);
        acc0[t] = fmaf(xv.z, wa.z, acc0[t]);
        acc0[t] = fmaf(xv.w, wa.w, acc0[t]);
        acc1[t] = fmaf(xv.x, wb.x, acc1[t]);
        acc1[t] = fmaf(xv.y, wb.y, acc1[t]);
        acc1[t] = fmaf(xv.z, wb.z, acc1[t]);
        acc1[t] = fmaf(xv.w, wb.w, acc1[t]);
      }
    }
  }
  __syncthreads();   // all xs reads done; sbuf now becomes g
  {
    int o0 = tid;
    float sc0 = bn_g[o0] * rsqrtf(bn_v[o0] + 1e-5f);
    float sh0 = fmaf(-bn_m[o0], sc0, bn_b[o0]);
#pragma unroll
    for (int t = 0; t < 12; ++t) {
      float z = fmaf(acc0[t], sc0, sh0);
      sbuf[o0 * 12 + t] = 0.5f * z * (1.f + erff(z * 0.70710678118654752f));
    }
    int o1 = tid + 512;
    float sc1 = bn_g[o1] * rsqrtf(bn_v[o1] + 1e-5f);
    float sh1 = fmaf(-bn_m[o1], sc1, bn_b[o1]);
#pragma unroll
    for (int t = 0; t < 12; ++t) {
      float z = fmaf(acc1[t], sc1, sh1);
      sbuf[o1 * 12 + t] = 0.5f * z * (1.f + erff(z * 0.70710678118654752f));
    }
  }
  __syncthreads();
  // sbuf (= g[o*12+t]) read-only from here.

  // ---------------- phase 3: lane = (sl, t) ----------------
  const int sl  = lane / 12;                 // 0..5 (5 = idle slot)
  const int t   = lane - sl * 12;            // 0..11 (0..3 for sl==5)
  const int slc = (sl < 5) ? sl : 4;         // clamped for reads
  const int rowi = (sl < 5) ? (t * 5 + sl) : (60 + t);
  float* Tw   = Tbuf + wave * (64 * 36);
  float* rowW = Tw + rowi * 36;
  const float tf = (float)t;

#pragma unroll 1
  for (int it = 0; it < 7; ++it) {
    const int s_raw = it * 40 + wave * 5 + sl;
    const bool valid = (sl < 5) && (s_raw < 256);
    const int s = valid ? s_raw : 0;

    // ---- h0 = g4 @ w_in.T + pos_encoding ----
    float h[64];
    {
      const int gb = s * 12 + t;
      const float g0 = sbuf[gb];
      const float g1 = sbuf[3072 + gb];
      const float g2 = sbuf[6144 + gb];
      const float g3 = sbuf[9216 + gb];
      float freq = 1.f;                       // exp(-2i*ln(1e4)/64)^i, i=0..31
#pragma unroll
      for (int i = 0; i < 32; ++i) {
        float ang = tf * freq;
        float sv = sinf(ang), cv = cosf(ang);
        const float* wi = w_in + 8 * i;
        h[2 * i]     = fmaf(g0, wi[0], fmaf(g1, wi[1], fmaf(g2, wi[2], fmaf(g3, wi[3], sv))));
        h[2 * i + 1] = fmaf(g0, wi[4], fmaf(g1, wi[5], fmaf(g2, wi[6], fmaf(g3, wi[7], cv))));
        freq *= 0.74989420933245580f;         // exp(-2*ln(1e4)/64)
      }
    }

#pragma unroll 1
    for (int l = 0; l < 2; ++l) {
      const float* Wb = qkv_w + l * 192 * 64;
      const float* Bb = qkv_b + l * 192;
      float att[2][12];
      float o[64];
#pragma unroll
      for (int d = 0; d < 64; ++d) o[d] = 0.f;

#pragma unroll
      for (int half = 0; half < 2; ++half) {
        // ---- K chunk (k dims half*32 .. +31) -> LDS words 0..31 ----
        LGKM0;
#pragma unroll 1
        for (int dp = 0; dp < 32; dp += 4) {
          int r = 64 + half * 32 + dp;
          float a0, a1, a2, a3;
          QUAD_MM(Wb + r * 64, Bb, r, a0, a1, a2, a3, h);
          *(float4*)(rowW + dp) = make_float4(a0, a1, a2, a3);
        }
        LGKM0;
        // ---- Q (heads 2*half, 2*half+1) fused with scores ----
#pragma unroll
        for (int hp = 0; hp < 2; ++hp) {
#pragma unroll
          for (int tk = 0; tk < 12; ++tk) att[hp][tk] = 0.f;
#pragma unroll 1
          for (int qq = 0; qq < 4; ++qq) {
            int r = half * 32 + hp * 16 + qq * 4;   // q row
            float a0, a1, a2, a3;
            QUAD_MM(Wb + r * 64, Bb, r, a0, a1, a2, a3, h);
            int w = hp * 16 + qq * 4;               // k word in row
#pragma unroll
            for (int tk = 0; tk < 12; ++tk) {
              const float4 kv = *(const float4*)(Tw + (tk * 5 + slc) * 36 + w);
              att[hp][tk] = fmaf(a0, kv.x, fmaf(a1, kv.y, fmaf(a2, kv.z, fmaf(a3, kv.w, att[hp][tk]))));
            }
          }
          // softmax (lane-local), scale 1/sqrt(16)=0.25 folded in
          float mx = att[hp][0];
#pragma unroll
          for (int tk = 1; tk < 12; ++tk) mx = fmaxf(mx, att[hp][tk]);
          float sum = 0.f;
#pragma unroll
          for (int tk = 0; tk < 12; ++tk) {
            float e = expf((att[hp][tk] - mx) * 0.25f);
            att[hp][tk] = e;
            sum += e;
          }
          float inv = 1.f / sum;
#pragma unroll
          for (int tk = 0; tk < 12; ++tk) att[hp][tk] *= inv;
        }
        // ---- V chunk (v dims half*32 .. +31) ----
        LGKM0;
#pragma unroll 1
        for (int dp = 0; dp < 32; dp += 4) {
          int r = 128 + half * 32 + dp;
          float a0, a1, a2, a3;
          QUAD_MM(Wb + r * 64, Bb, r, a0, a1, a2, a3, h);
          *(float4*)(rowW + dp) = make_float4(a0, a1, a2, a3);
        }
        LGKM0;
        // ---- PV: o[half*32 .. +31] ----
#pragma unroll
        for (int tk = 0; tk < 12; ++tk) {
          const float* vr = Tw + (tk * 5 + slc) * 36;
          float a0 = att[0][tk], a1 = att[1][tk];
#pragma unroll
          for (int dq = 0; dq < 8; ++dq) {
            float4 vv = *(const float4*)(vr + dq * 4);
            float aa = (dq < 4) ? a0 : a1;
            int ob_ = half * 32 + dq * 4;
            o[ob_ + 0] = fmaf(aa, vv.x, o[ob_ + 0]);
            o[ob_ + 1] = fmaf(aa, vv.y, o[ob_ + 1]);
            o[ob_ + 2] = fmaf(aa, vv.z, o[ob_ + 2]);
            o[ob_ + 3] = fmaf(aa, vv.w, o[ob_ + 3]);
          }
        }
      } // half

      // ---- o-proj + residual (two halves through LDS row) ----
      {
        const float* WO  = ow + l * 64 * 64;
        const float* BOp = ob + l * 64;
#pragma unroll
        for (int half = 0; half < 2; ++half) {
          LGKM0;
#pragma unroll 1
          for (int dp = 0; dp < 32; dp += 4) {
            int r = half * 32 + dp;
            float a0, a1, a2, a3;
            QUAD_MM(WO + r * 64, BOp, r, a0, a1, a2, a3, o);
            *(float4*)(rowW + dp) = make_float4(a0, a1, a2, a3);
          }
          LGKM0;
#pragma unroll
          for (int dq = 0; dq < 8; ++dq) {
            float4 r4 = *(const float4*)(rowW + dq * 4);
            int hb = half * 32 + dq * 4;
            h[hb + 0] += r4.x;
            h[hb + 1] += r4.y;
            h[hb + 2] += r4.z;
            h[hb + 3] += r4.w;
          }
        }
      }
      // ---- LN1 ----
      LAYERNORM(ln1_g + l * 64, ln1_b + l * 64);

      // ---- FF: chunks of 32 ff-dims through LDS row ----
      {
        float facc[64];
#pragma unroll
        for (int d = 0; d < 64; ++d) facc[d] = ff2_b[l * 64 + d];
        const float* W1 = ff1_w + l * 256 * 64;
        const float* B1 = ff1_b + l * 256;
        const float* W2 = ff2_w + l * 64 * 256;
#pragma unroll 1
        for (int chk = 0; chk < 8; ++chk) {
          LGKM0;
#pragma unroll 1
          for (int fp = 0; fp < 32; fp += 4) {
            int r = chk * 32 + fp;
            float a0, a1, a2, a3;
            QUAD_MM(W1 + r * 64, B1, r, a0, a1, a2, a3, h);
            a0 = fmaxf(a0, 0.f);
            a1 = fmaxf(a1, 0.f);
            a2 = fmaxf(a2, 0.f);
            a3 = fmaxf(a3, 0.f);
            *(float4*)(rowW + fp) = make_float4(a0, a1, a2, a3);
          }
          LGKM0;
#pragma unroll 1
          for (int sub = 0; sub < 4; ++sub) {
            float4 xa = *(const float4*)(rowW + sub * 8);
            float4 xb = *(const float4*)(rowW + sub * 8 + 4);
            int cb = chk * 32 + sub * 8;
#pragma unroll
            for (int d2 = 0; d2 < 64; ++d2) {
              const float* w2r = W2 + d2 * 256 + cb;
              float t0 = fmaf(w2r[0], xa.x, facc[d2]);
              t0 = fmaf(w2r[1], xa.y, t0);
              t0 = fmaf(w2r[2], xa.z, t0);
              t0 = fmaf(w2r[3], xa.w, t0);
              t0 = fmaf(w2r[4], xb.x, t0);
              t0 = fmaf(w2r[5], xb.y, t0);
              t0 = fmaf(w2r[6], xb.z, t0);
              facc[d2] = fmaf(w2r[7], xb.w, t0);
            }
          }
        }
#pragma unroll
        for (int d = 0; d < 64; ++d) h[d] += facc[d];
      }
      // ---- LN2 ----
      LAYERNORM(ln2_g + l * 64, ln2_b + l * 64);
    } // layer

    // ---- head: mean over t, dot w_out, sigmoid ----
    {
      float p = 0.f;
#pragma unroll
      for (int d = 0; d < 64; ++d) p = fmaf(h[d], w_out[d], p);
      LGKM0;
      rowW[0] = p;
      LGKM0;
      float ps = 0.f;
#pragma unroll
      for (int tk = 0; tk < 12; ++tk) ps += Tw[(tk * 5 + slc) * 36];
      if (valid && t == 0) {
        float logit = ps * (1.f / 12.f) + b_out[0];
        int hf = ((sp >> 4) << 4) | (s_raw >> 4);
        int wf = ((sp & 15) << 4) | (s_raw & 15);
        out[hf * 256 + wf] = 1.f / (1.f + expf(-logit));
      }
    }
  } // pass loop
}

extern "C" void kernel_launch(void* const* d_in, const int* in_sizes, int n_in,
                              void* d_out, int out_size, void* d_ws, size_t ws_size,
                              hipStream_t stream) {
  (void)in_sizes; (void)n_in; (void)d_ws; (void)ws_size; (void)out_size;
  prithvi_fused<<<256, 512, 0, stream>>>(
    (const float*)d_in[0],  (const float*)d_in[1],  (const float*)d_in[2],
    (const float*)d_in[3],  (const float*)d_in[4],  (const float*)d_in[5],
    (const float*)d_in[6],  (const float*)d_in[7],  (const float*)d_in[8],
    (const float*)d_in[9],  (const float*)d_in[10], (const float*)d_in[11],
    (const float*)d_in[12], (const float*)d_in[13], (const float*)d_in[14],
    (const float*)d_in[15], (const float*)d_in[16], (const float*)d_in[17],
    (const float*)d_in[18], (const float*)d_in[19], (const float*)d_in[20],
    (float*)d_out);
}

// Round 6
// 3948.911 us; speedup vs baseline: 1.6884x; 1.6884x over previous
//
#include <hip/hip_runtime.h>
#include <math.h>

// E=1024, T=12, CPT=4, D=64, NH=4, HD=16, FF=256, L=2
// R5 restructure: phase-3 lane = model-dim column d' (64 lanes), one seq at a
// time per wave (32 seqs/wave). Per-lane state ~100 floats -> fits the 128-VGPR
// cap the compiler insists on (R1/R2/R4 all pinned at 128 w/ 7GB spill traffic).
// Cross-lane h/f sharing via wave-uniform LDS broadcast reads (3KB bufs);
// weights pre-transposed into d_ws so weight reads are coalesced b32/lane.

#define LGKM0 asm volatile("s_waitcnt lgkmcnt(0)" ::: "memory")

// ---- weight transpose prologue: ws layout (floats) ----
// [0)      qkvT[l][d][r]  2*64*192 = 24576
// [24576)  owT [l][d][r]  2*64*64  =  8192
// [32768)  f1T [l][d][ff] 2*64*256 = 32768
// [65536)  f2T [l][f][dd] 2*256*64 = 32768   total 98304 floats = 384KB
__global__ void wtrans(const float* __restrict__ qkv_w, const float* __restrict__ ow,
                       const float* __restrict__ ff1_w, const float* __restrict__ ff2_w,
                       float* __restrict__ ws) {
  int idx = blockIdx.x * 256 + threadIdx.x;
  if (idx < 24576) {
    int l = idx / 12288, rem = idx % 12288, d = rem / 192, r = rem % 192;
    ws[idx] = qkv_w[l * 12288 + r * 64 + d];
  } else if (idx < 32768) {
    int j = idx - 24576; int l = j / 4096, rem = j % 4096, d = rem / 64, r = rem % 64;
    ws[idx] = ow[l * 4096 + r * 64 + d];
  } else if (idx < 65536) {
    int j = idx - 32768; int l = j / 16384, rem = j % 16384, d = rem / 256, r = rem % 256;
    ws[idx] = ff1_w[l * 16384 + r * 64 + d];
  } else if (idx < 98304) {
    int j = idx - 65536; int l = j / 16384, rem = j % 16384, f = rem / 64, dd = rem % 64;
    ws[idx] = ff2_w[l * 16384 + dd * 256 + f];
  }
}

// LayerNorm over d (lanes) for h[12] in regs; 6+6 butterfly per t.
#define LNORM(GV, BV)                                                        \
  {                                                                          \
    _Pragma("unroll") for (int t_ = 0; t_ < 12; ++t_) {                      \
      float sm_ = h[t_];                                                     \
      _Pragma("unroll") for (int of_ = 1; of_ < 64; of_ <<= 1)               \
          sm_ += __shfl_xor(sm_, of_);                                       \
      float mean_ = sm_ * (1.f / 64.f);                                      \
      float dl_ = h[t_] - mean_;                                             \
      float vs_ = dl_ * dl_;                                                 \
      _Pragma("unroll") for (int of_ = 1; of_ < 64; of_ <<= 1)               \
          vs_ += __shfl_xor(vs_, of_);                                       \
      h[t_] = fmaf(dl_ * rsqrtf(vs_ * (1.f / 64.f) + 1e-5f), (GV), (BV));    \
    }                                                                        \
  }

__global__ __launch_bounds__(512) void prithvi_fused(
    const float* __restrict__ x,     const float* __restrict__ conv_w,
    const float* __restrict__ bn_g,  const float* __restrict__ bn_b,
    const float* __restrict__ bn_m,  const float* __restrict__ bn_v,
    const float* __restrict__ w_in,  const float* __restrict__ qkv_b,
    const float* __restrict__ ob,    const float* __restrict__ ln1_g,
    const float* __restrict__ ln1_b, const float* __restrict__ ff1_b,
    const float* __restrict__ ff2_b, const float* __restrict__ ln2_g,
    const float* __restrict__ ln2_b, const float* __restrict__ w_out,
    const float* __restrict__ b_out, const float* __restrict__ ws,
    float* __restrict__ out)
{
  __shared__ __align__(16) float sbuf[12288];   // 48KB: xs then g[o*12+t]
  __shared__ __align__(16) float Pbuf[24576];   // 96KB: 8 waves x {h,k,v,sh}x768

  const int sp   = blockIdx.x;
  const int tid  = threadIdx.x;
  const int lane = tid & 63;
  const int wave = tid >> 6;

  // ---------------- phase 1: stage x slice transposed: sbuf[t*1024+e] ----
  for (int ch = tid; ch < 12288; ch += 512) {
    int e = ch / 12;
    int t = ch - e * 12;
    sbuf[t * 1024 + e] = x[(size_t)ch * 256 + sp];
  }
  __syncthreads();

  // ---------------- phase 2: 1x1 conv + BN + GELU -> sbuf[o*12+t] --------
  {
    float acc0[12], acc1[12];
#pragma unroll
    for (int t = 0; t < 12; ++t) { acc0[t] = 0.f; acc1[t] = 0.f; }
    const float* w0p = conv_w + tid * 1024;
    const float* w1p = conv_w + (tid + 512) * 1024;
    for (int eb = 0; eb < 1024; eb += 4) {
      float4 wa = *(const float4*)(w0p + eb);
      float4 wb = *(const float4*)(w1p + eb);
#pragma unroll
      for (int t = 0; t < 12; ++t) {
        float4 xv = *(const float4*)&sbuf[t * 1024 + eb];
        acc0[t] = fmaf(xv.x, wa.x, acc0[t]);
        acc0[t] = fmaf(xv.y, wa.y, acc0[t]);
        acc0[t] = fmaf(xv.z, wa.z, acc0[t]);
        acc0[t] = fmaf(xv.w, wa.w, acc0[t]);
        acc1[t] = fmaf(xv.x, wb.x, acc1[t]);
        acc1[t] = fmaf(xv.y, wb.y, acc1[t]);
        acc1[t] = fmaf(xv.z, wb.z, acc1[t]);
        acc1[t] = fmaf(xv.w, wb.w, acc1[t]);
      }
    }
    __syncthreads();
    {
      int o0 = tid;
      float sc0 = bn_g[o0] * rsqrtf(bn_v[o0] + 1e-5f);
      float sh0 = fmaf(-bn_m[o0], sc0, bn_b[o0]);
#pragma unroll
      for (int t = 0; t < 12; ++t) {
        float z = fmaf(acc0[t], sc0, sh0);
        sbuf[o0 * 12 + t] = 0.5f * z * (1.f + erff(z * 0.70710678118654752f));
      }
      int o1 = tid + 512;
      float sc1 = bn_g[o1] * rsqrtf(bn_v[o1] + 1e-5f);
      float sh1 = fmaf(-bn_m[o1], sc1, bn_b[o1]);
#pragma unroll
      for (int t = 0; t < 12; ++t) {
        float z = fmaf(acc1[t], sc1, sh1);
        sbuf[o1 * 12 + t] = 0.5f * z * (1.f + erff(z * 0.70710678118654752f));
      }
    }
  }
  __syncthreads();   // sbuf = g, read-only from here

  // ---------------- phase 3 ----------------
  float* hB  = Pbuf + wave * 3072;       // h  [t][64]
  float* kB  = hB + 768;                 // k  [t][64]
  float* vB  = hB + 1536;                // v  [t][64]
  float* shB = hB + 2304;                // q -> o -> f chunk [t][64]

  const float wi0 = w_in[lane * 4 + 0], wi1 = w_in[lane * 4 + 1],
              wi2 = w_in[lane * 4 + 2], wi3 = w_in[lane * 4 + 3];
  const float wo_lane = w_out[lane];
  const float bout = b_out[0];
  float pe[12];
  {
    float freq = expf(-(float)(lane & ~1) * (9.210340371976184f / 64.f));
#pragma unroll
    for (int t = 0; t < 12; ++t) {
      float a = freq * (float)t;
      pe[t] = (lane & 1) ? cosf(a) : sinf(a);
    }
  }

#pragma unroll 1
  for (int i = 0; i < 32; ++i) {
    const int s = wave * 32 + i;

    // ---- h0 = g @ w_in.T + pe ----
    float h[12];
#pragma unroll
    for (int t = 0; t < 12; ++t) {
      float g0 = sbuf[(0 * 256 + s) * 12 + t];
      float g1 = sbuf[(1 * 256 + s) * 12 + t];
      float g2 = sbuf[(2 * 256 + s) * 12 + t];
      float g3 = sbuf[(3 * 256 + s) * 12 + t];
      h[t] = fmaf(g0, wi0, fmaf(g1, wi1, fmaf(g2, wi2, fmaf(g3, wi3, pe[t]))));
    }
    LGKM0;
#pragma unroll
    for (int t = 0; t < 12; ++t) hB[t * 64 + lane] = h[t];
    LGKM0;

#pragma unroll 1
    for (int l = 0; l < 2; ++l) {
      // ---- qkv: lane owns q/k/v column `lane` ----
      {
        const float* Wq = ws + l * 12288;   // [d][192]
        float q[12], k[12], v[12];
        {
          float b0 = qkv_b[l * 192 + lane];
          float b1 = qkv_b[l * 192 + 64 + lane];
          float b2 = qkv_b[l * 192 + 128 + lane];
#pragma unroll
          for (int t = 0; t < 12; ++t) { q[t] = b0; k[t] = b1; v[t] = b2; }
        }
#pragma unroll 1
        for (int d = 0; d < 64; d += 2) {
          float2 hb[12];
#pragma unroll
          for (int t = 0; t < 12; ++t) hb[t] = *(const float2*)(hB + t * 64 + d);
          const float* wr = Wq + d * 192 + lane;
          float wq0 = wr[0],   wk0 = wr[64],  wv0 = wr[128];
          float wq1 = wr[192], wk1 = wr[256], wv1 = wr[320];
#pragma unroll
          for (int t = 0; t < 12; ++t) {
            q[t] = fmaf(hb[t].x, wq0, fmaf(hb[t].y, wq1, q[t]));
            k[t] = fmaf(hb[t].x, wk0, fmaf(hb[t].y, wk1, k[t]));
            v[t] = fmaf(hb[t].x, wv0, fmaf(hb[t].y, wv1, v[t]));
          }
        }
        LGKM0;
#pragma unroll
        for (int t = 0; t < 12; ++t) {
          shB[t * 64 + lane] = q[t];
          kB[t * 64 + lane]  = k[t];
          vB[t * 64 + lane]  = v[t];
        }
        LGKM0;
      }

      // ---- attention: lanes 0..47 = (head, tq) ----
      {
        const int hh = lane / 12;
        const int tq = lane - hh * 12;
        if (lane < 48) {
          float qr[16];
#pragma unroll
          for (int e = 0; e < 16; e += 4) {
            float4 q4 = *(const float4*)(shB + tq * 64 + hh * 16 + e);
            qr[e] = q4.x; qr[e + 1] = q4.y; qr[e + 2] = q4.z; qr[e + 3] = q4.w;
          }
          float att[12];
#pragma unroll
          for (int tk = 0; tk < 12; ++tk) {
            float ssv = 0.f;
#pragma unroll
            for (int e = 0; e < 16; e += 4) {
              float4 k4 = *(const float4*)(kB + tk * 64 + hh * 16 + e);
              ssv = fmaf(qr[e], k4.x, fmaf(qr[e + 1], k4.y,
                    fmaf(qr[e + 2], k4.z, fmaf(qr[e + 3], k4.w, ssv))));
            }
            att[tk] = ssv;
          }
          float mx = att[0];
#pragma unroll
          for (int tk = 1; tk < 12; ++tk) mx = fmaxf(mx, att[tk]);
          float ssum = 0.f;
#pragma unroll
          for (int tk = 0; tk < 12; ++tk) {
            float e_ = expf((att[tk] - mx) * 0.25f);
            att[tk] = e_; ssum += e_;
          }
          float inv = 1.f / ssum;
          float oa[16];
#pragma unroll
          for (int e = 0; e < 16; ++e) oa[e] = 0.f;
#pragma unroll
          for (int tk = 0; tk < 12; ++tk) {
            float a_ = att[tk] * inv;
#pragma unroll
            for (int e = 0; e < 16; e += 4) {
              float4 v4 = *(const float4*)(vB + tk * 64 + hh * 16 + e);
              oa[e]     = fmaf(a_, v4.x, oa[e]);
              oa[e + 1] = fmaf(a_, v4.y, oa[e + 1]);
              oa[e + 2] = fmaf(a_, v4.z, oa[e + 2]);
              oa[e + 3] = fmaf(a_, v4.w, oa[e + 3]);
            }
          }
#pragma unroll
          for (int e = 0; e < 16; e += 4)
            *(float4*)(shB + tq * 64 + hh * 16 + e) =
                make_float4(oa[e], oa[e + 1], oa[e + 2], oa[e + 3]);
        }
        LGKM0;
      }

      // ---- o-proj + residual ----
      {
        const float* Wo = ws + 24576 + l * 4096;   // [d][64]
        float p[12];
        float b_ = ob[l * 64 + lane];
#pragma unroll
        for (int t = 0; t < 12; ++t) p[t] = b_;
#pragma unroll 1
        for (int d = 0; d < 64; d += 4) {
          float4 ov[12];
#pragma unroll
          for (int t = 0; t < 12; ++t) ov[t] = *(const float4*)(shB + t * 64 + d);
          const float* wr = Wo + d * 64 + lane;
          float w0 = wr[0], w1 = wr[64], w2 = wr[128], w3 = wr[192];
#pragma unroll
          for (int t = 0; t < 12; ++t)
            p[t] = fmaf(ov[t].x, w0, fmaf(ov[t].y, w1,
                   fmaf(ov[t].z, w2, fmaf(ov[t].w, w3, p[t]))));
        }
#pragma unroll
        for (int t = 0; t < 12; ++t) h[t] += p[t];
      }
      // ---- LN1 ----
      LNORM(ln1_g[l * 64 + lane], ln1_b[l * 64 + lane]);
      LGKM0;
#pragma unroll
      for (int t = 0; t < 12; ++t) hB[t * 64 + lane] = h[t];
      LGKM0;

      // ---- FF: 4 passes of 64 ff-cols (1 col/lane) ----
      {
        float facc[12];
        float b2_ = ff2_b[l * 64 + lane];
#pragma unroll
        for (int t = 0; t < 12; ++t) facc[t] = b2_;
        const float* W1 = ws + 32768 + l * 16384;   // [d][256]
        const float* W2 = ws + 65536 + l * 16384;   // [f][64]
#pragma unroll 1
        for (int p4 = 0; p4 < 4; ++p4) {
          float f[12];
          float b1_ = ff1_b[l * 256 + p4 * 64 + lane];
#pragma unroll
          for (int t = 0; t < 12; ++t) f[t] = b1_;
#pragma unroll 1
          for (int d = 0; d < 64; d += 4) {
            float4 hb4[12];
#pragma unroll
            for (int t = 0; t < 12; ++t) hb4[t] = *(const float4*)(hB + t * 64 + d);
            const float* wr = W1 + d * 256 + p4 * 64 + lane;
            float w0 = wr[0], w1 = wr[256], w2 = wr[512], w3 = wr[768];
#pragma unroll
            for (int t = 0; t < 12; ++t)
              f[t] = fmaf(hb4[t].x, w0, fmaf(hb4[t].y, w1,
                     fmaf(hb4[t].z, w2, fmaf(hb4[t].w, w3, f[t]))));
          }
#pragma unroll
          for (int t = 0; t < 12; ++t) f[t] = fmaxf(f[t], 0.f);
          LGKM0;
#pragma unroll
          for (int t = 0; t < 12; ++t) shB[t * 64 + lane] = f[t];
          LGKM0;
          const float* W2p = W2 + (p4 * 64) * 64 + lane;
#pragma unroll 1
          for (int fi = 0; fi < 64; fi += 4) {
            float4 fb[12];
#pragma unroll
            for (int t = 0; t < 12; ++t) fb[t] = *(const float4*)(shB + t * 64 + fi);
            const float* wr2 = W2p + fi * 64;
            float w0 = wr2[0], w1 = wr2[64], w2 = wr2[128], w3 = wr2[192];
#pragma unroll
            for (int t = 0; t < 12; ++t)
              facc[t] = fmaf(fb[t].x, w0, fmaf(fb[t].y, w1,
                        fmaf(fb[t].z, w2, fmaf(fb[t].w, w3, facc[t]))));
          }
        }
#pragma unroll
        for (int t = 0; t < 12; ++t) h[t] += facc[t];
      }
      // ---- LN2 ----
      LNORM(ln2_g[l * 64 + lane], ln2_b[l * 64 + lane]);
      LGKM0;
#pragma unroll
      for (int t = 0; t < 12; ++t) hB[t * 64 + lane] = h[t];
      LGKM0;
    } // layer

    // ---- head ----
    {
      float msum = 0.f;
#pragma unroll
      for (int t = 0; t < 12; ++t) msum += h[t];
      float c = msum * (1.f / 12.f) * wo_lane;
#pragma unroll
      for (int of = 1; of < 64; of <<= 1) c += __shfl_xor(c, of);
      if (lane == 0) {
        float logit = c + bout;
        int hf = ((sp >> 4) << 4) | (s >> 4);
        int wf = ((sp & 15) << 4) | (s & 15);
        out[hf * 256 + wf] = 1.f / (1.f + expf(-logit));
      }
    }
  } // seq loop
}

extern "C" void kernel_launch(void* const* d_in, const int* in_sizes, int n_in,
                              void* d_out, int out_size, void* d_ws, size_t ws_size,
                              hipStream_t stream) {
  (void)in_sizes; (void)n_in; (void)out_size; (void)ws_size;
  float* ws = (float*)d_ws;
  wtrans<<<384, 256, 0, stream>>>(
      (const float*)d_in[7],  (const float*)d_in[9],
      (const float*)d_in[13], (const float*)d_in[15], ws);
  prithvi_fused<<<256, 512, 0, stream>>>(
      (const float*)d_in[0],  (const float*)d_in[1],  (const float*)d_in[2],
      (const float*)d_in[3],  (const float*)d_in[4],  (const float*)d_in[5],
      (const float*)d_in[6],  (const float*)d_in[8],  (const float*)d_in[10],
      (const float*)d_in[11], (const float*)d_in[12], (const float*)d_in[14],
      (const float*)d_in[16], (const float*)d_in[17], (const float*)d_in[18],
      (const float*)d_in[19], (const float*)d_in[20], ws,
      (float*)d_out);
}

// Round 7
// 1454.516 us; speedup vs baseline: 4.5839x; 2.7149x over previous
//
#include <hip/hip_runtime.h>
#include <math.h>

// R6: MFMA rewrite. Per wave = one sequence (12 tokens padded to 16 rows).
// QKV / O-proj / FF1 / FF2 via mfma_f32_16x16x32_bf16 (A from LDS bf16,
// B = weight fragments pre-packed in d_ws by wpack prologue).
// Scores / PV via mfma_f32_16x16x16bf16_1k (K = 16 = head dim).
// Residual stream fp32 in registers (C-frag layout: d = j*16+(lane&15),
// t = (lane>>4)*4+i); LN + softmax fp32 via 16-lane shfl_xor.

typedef __attribute__((ext_vector_type(8))) short s8v;
typedef __attribute__((ext_vector_type(4))) short s4v;
typedef __attribute__((ext_vector_type(4))) float f4v;
typedef __attribute__((ext_vector_type(4))) unsigned int u4v;

#define MFMA32(A, B, C) __builtin_amdgcn_mfma_f32_16x16x32_bf16((A), (B), (C), 0, 0, 0)
#define MFMA16(A, B, C) __builtin_amdgcn_mfma_f32_16x16x16bf16_1k((A), (B), (C), 0, 0, 0)

static __device__ __forceinline__ unsigned short f2b(float f) {
  unsigned u = __builtin_bit_cast(unsigned, f);
  u += 0x7fffu + ((u >> 16) & 1u);
  return (unsigned short)(u >> 16);
}
static __device__ __forceinline__ float b2f(unsigned short h) {
  return __builtin_bit_cast(float, ((unsigned)h) << 16);
}

// ---- prologue: pack weights into MFMA B-fragment order (bf16) ----
// tile t: lane l holds B[k = kk*32 + (l>>4)*8 + e][n = j*16 + (l&15)], e=0..7
// tile bases: qkv l*24 + kk*12 + j | ow 48 + l*8 + kk*4 + j
//             ff1 64 + l*32 + kk*16 + j | ff2 128 + l*32 + kk*4 + j (kk 0..7)
__global__ __launch_bounds__(256) void wpack(
    const float* __restrict__ qkv_w, const float* __restrict__ ow,
    const float* __restrict__ ff1_w, const float* __restrict__ ff2_w,
    unsigned int* __restrict__ ws) {
  int gid = blockIdx.x * 256 + threadIdx.x;   // 0..12287
  int tIdx = gid >> 6, lane = gid & 63;
  int ln = lane & 15, grp = lane >> 4;
  const float* src;
  if (tIdx < 48) {
    int l = tIdx / 24, r = tIdx % 24, kk = r / 12, j = r % 12;
    src = qkv_w + l * 12288 + (j * 16 + ln) * 64 + kk * 32 + grp * 8;
  } else if (tIdx < 64) {
    int u = tIdx - 48, l = u / 8, r = u % 8, kk = r / 4, j = r % 4;
    src = ow + l * 4096 + (j * 16 + ln) * 64 + kk * 32 + grp * 8;
  } else if (tIdx < 128) {
    int u = tIdx - 64, l = u / 32, r = u % 32, kk = r / 16, j = r % 16;
    src = ff1_w + l * 16384 + (j * 16 + ln) * 64 + kk * 32 + grp * 8;
  } else {
    int u = tIdx - 128, l = u / 32, r = u % 32, kk = r / 4, j = r % 4;
    src = ff2_w + l * 16384 + (j * 16 + ln) * 256 + kk * 32 + grp * 8;
  }
  unsigned p[4];
#pragma unroll
  for (int e = 0; e < 4; ++e)
    p[e] = (unsigned)f2b(src[2 * e]) | ((unsigned)f2b(src[2 * e + 1]) << 16);
  u4v val = {p[0], p[1], p[2], p[3]};
  *(u4v*)(ws + (size_t)gid * 4) = val;
}

__global__ __launch_bounds__(512) void prithvi_fused(
    const float* __restrict__ x,     const float* __restrict__ conv_w,
    const float* __restrict__ bn_g,  const float* __restrict__ bn_b,
    const float* __restrict__ bn_m,  const float* __restrict__ bn_v,
    const float* __restrict__ w_in,  const float* __restrict__ qkv_b,
    const float* __restrict__ ob,    const float* __restrict__ ln1_g,
    const float* __restrict__ ln1_b, const float* __restrict__ ff1_b,
    const float* __restrict__ ff2_b, const float* __restrict__ ln2_g,
    const float* __restrict__ ln2_b, const float* __restrict__ w_out,
    const float* __restrict__ b_out, const float* __restrict__ ws,
    float* __restrict__ out)
{
  __shared__ __align__(16) float xsg[12288];     // 48KB: xs fp32, then g bf16 (first 24KB)
  __shared__ __align__(16) char WBuf[8][13824];  // per-wave: HB|QB|KB|VB|F

  const int sp = blockIdx.x, tid = threadIdx.x;
  const int lane = tid & 63, wave = tid >> 6;

  // ---------------- phase 1: stage x slice transposed: xsg[t*1024+e] ----
  for (int ch = tid; ch < 12288; ch += 512) {
    int e = ch / 12, t = ch - e * 12;
    xsg[t * 1024 + e] = x[(size_t)ch * 256 + sp];
  }
  __syncthreads();

  // ---------------- phase 2: 1x1 conv + BN + GELU -> g bf16 [o][t] ------
  {
    float acc0[12], acc1[12];
#pragma unroll
    for (int t = 0; t < 12; ++t) { acc0[t] = 0.f; acc1[t] = 0.f; }
    const float* w0p = conv_w + tid * 1024;
    const float* w1p = conv_w + (tid + 512) * 1024;
    for (int eb = 0; eb < 1024; eb += 4) {
      float4 wa = *(const float4*)(w0p + eb);
      float4 wb = *(const float4*)(w1p + eb);
#pragma unroll
      for (int t = 0; t < 12; ++t) {
        float4 xv = *(const float4*)&xsg[t * 1024 + eb];
        acc0[t] = fmaf(xv.x, wa.x, acc0[t]);
        acc0[t] = fmaf(xv.y, wa.y, acc0[t]);
        acc0[t] = fmaf(xv.z, wa.z, acc0[t]);
        acc0[t] = fmaf(xv.w, wa.w, acc0[t]);
        acc1[t] = fmaf(xv.x, wb.x, acc1[t]);
        acc1[t] = fmaf(xv.y, wb.y, acc1[t]);
        acc1[t] = fmaf(xv.z, wb.z, acc1[t]);
        acc1[t] = fmaf(xv.w, wb.w, acc1[t]);
      }
    }
    __syncthreads();   // all xs reads done; first 24KB of xsg becomes g (bf16)
    unsigned short* gW = (unsigned short*)xsg;
    {
      int o0 = tid;
      float sc0 = bn_g[o0] * rsqrtf(bn_v[o0] + 1e-5f);
      float sh0 = fmaf(-bn_m[o0], sc0, bn_b[o0]);
#pragma unroll
      for (int t = 0; t < 12; ++t) {
        float z = fmaf(acc0[t], sc0, sh0);
        gW[o0 * 12 + t] = f2b(0.5f * z * (1.f + erff(z * 0.70710678118654752f)));
      }
      int o1 = tid + 512;
      float sc1 = bn_g[o1] * rsqrtf(bn_v[o1] + 1e-5f);
      float sh1 = fmaf(-bn_m[o1], sc1, bn_b[o1]);
#pragma unroll
      for (int t = 0; t < 12; ++t) {
        float z = fmaf(acc1[t], sc1, sh1);
        gW[o1 * 12 + t] = f2b(0.5f * z * (1.f + erff(z * 0.70710678118654752f)));
      }
    }
  }
  __syncthreads();   // g read-only from here

  // ---------------- phase 3 ----------------
  const int ln = lane & 15, grp = lane >> 4;
  char* Wb = &WBuf[wave][0];
  unsigned short* HBh = (unsigned short*)Wb;            // [16][72] bf16, stride 144B
  unsigned short* QBh = (unsigned short*)(Wb + 2304);   // Q then P
  unsigned short* KBh = (unsigned short*)(Wb + 4608);   // K then O
  char* VBp = Wb + 6912;                                 // V^T [64][40B]
  unsigned short* Fh  = (unsigned short*)(Wb + 9472);   // [16][136] bf16, stride 272B
  const unsigned short* gB = (const unsigned short*)xsg;
  const u4v* WS = (const u4v*)ws;
#define BT(T) __builtin_bit_cast(s8v, WS[(T) * 64 + lane])

  // pe[i][j] for t=grp*4+i, d=j*16+ln ; w_in rows
  float pe[4][4], wic[4][4];
#pragma unroll
  for (int j = 0; j < 4; ++j) {
    int d = j * 16 + ln;
    float freq = expf(-(float)(d & ~1) * (9.210340371976184f / 64.f));
#pragma unroll
    for (int i = 0; i < 4; ++i) {
      float a = freq * (float)(grp * 4 + i);
      pe[i][j] = (d & 1) ? cosf(a) : sinf(a);
    }
#pragma unroll
    for (int c = 0; c < 4; ++c) wic[j][c] = w_in[d * 4 + c];
  }
  float wo4[4];
#pragma unroll
  for (int j = 0; j < 4; ++j) wo4[j] = w_out[j * 16 + ln];
  const float bo0 = b_out[0];

#pragma unroll 1
  for (int it = 0; it < 32; ++it) {
    const int s = wave * 32 + it;
    f4v v[4];

    // ---- h0 (C-frag layout, fp32 in regs) + write HB bf16 ----
    {
      int tb = (grp < 3) ? grp * 4 : 0;   // clamp pad rows' g-reads in-bounds
#pragma unroll
      for (int i = 0; i < 4; ++i) {
        float g0 = b2f(gB[        s * 12 + tb + i]);
        float g1 = b2f(gB[3072 +  s * 12 + tb + i]);
        float g2 = b2f(gB[6144 +  s * 12 + tb + i]);
        float g3 = b2f(gB[9216 +  s * 12 + tb + i]);
#pragma unroll
        for (int j = 0; j < 4; ++j)
          v[j][i] = fmaf(g0, wic[j][0], fmaf(g1, wic[j][1],
                    fmaf(g2, wic[j][2], fmaf(g3, wic[j][3], pe[i][j]))));
      }
#pragma unroll
      for (int i = 0; i < 4; ++i)
#pragma unroll
        for (int j = 0; j < 4; ++j)
          HBh[(grp * 4 + i) * 72 + j * 16 + ln] = f2b(v[j][i]);
    }

#pragma unroll 1
    for (int l = 0; l < 2; ++l) {
      // ---- QKV ----
      {
        s8v a0 = *(const s8v*)((const char*)HBh + ln * 144 + grp * 16);
        s8v a1 = *(const s8v*)((const char*)HBh + ln * 144 + 64 + grp * 16);
#pragma unroll
        for (int j = 0; j < 12; ++j) {
          float bb = qkv_b[l * 192 + j * 16 + ln];
          f4v c = {bb, bb, bb, bb};
          c = MFMA32(a0, BT(l * 24 + j), c);
          c = MFMA32(a1, BT(l * 24 + 12 + j), c);
          if (j < 4) {
#pragma unroll
            for (int i = 0; i < 4; ++i)
              QBh[(grp * 4 + i) * 72 + j * 16 + ln] = f2b(c[i]);
          } else if (j < 8) {
#pragma unroll
            for (int i = 0; i < 4; ++i)
              KBh[(grp * 4 + i) * 72 + (j - 4) * 16 + ln] = f2b(c[i]);
          } else {
            unsigned lo = (unsigned)f2b(c[0]) | ((unsigned)f2b(c[1]) << 16);
            unsigned hi = (unsigned)f2b(c[2]) | ((unsigned)f2b(c[3]) << 16);
            *(uint2*)(VBp + ((j - 8) * 16 + ln) * 40 + grp * 8) = make_uint2(lo, hi);
          }
        }
      }
      // ---- attention: per head, scores->softmax->P->PV->O ----
      {
        const bool padk = (ln >= 12);
        f4v z4 = {0.f, 0.f, 0.f, 0.f};
#pragma unroll
        for (int hh = 0; hh < 4; ++hh) {
          s4v aq = *(const s4v*)((const char*)QBh + ln * 144 + hh * 32 + grp * 8);
          s4v bk = *(const s4v*)((const char*)KBh + ln * 144 + hh * 32 + grp * 8);
          f4v sc = MFMA16(aq, bk, z4);
#pragma unroll
          for (int i = 0; i < 4; ++i) {
            float si = padk ? -1e30f : sc[i] * 0.25f;
            float mx = si;
            mx = fmaxf(mx, __shfl_xor(mx, 1));
            mx = fmaxf(mx, __shfl_xor(mx, 2));
            mx = fmaxf(mx, __shfl_xor(mx, 4));
            mx = fmaxf(mx, __shfl_xor(mx, 8));
            float e = expf(si - mx);
            float sm = e;
            sm += __shfl_xor(sm, 1);
            sm += __shfl_xor(sm, 2);
            sm += __shfl_xor(sm, 4);
            sm += __shfl_xor(sm, 8);
            QBh[(grp * 4 + i) * 72 + hh * 16 + ln] = f2b(e / sm);  // P (pads -> 0)
          }
          s4v ap = *(const s4v*)((const char*)QBh + ln * 144 + hh * 32 + grp * 8);
          s4v bv = *(const s4v*)(VBp + (hh * 16 + ln) * 40 + grp * 8);
          f4v o = MFMA16(ap, bv, z4);
#pragma unroll
          for (int i = 0; i < 4; ++i)
            KBh[(grp * 4 + i) * 72 + hh * 16 + ln] = f2b(o[i]);   // O over K
        }
      }
      // ---- O-proj + residual + LN1 ----
      {
        s8v a0 = *(const s8v*)((const char*)KBh + ln * 144 + grp * 16);
        s8v a1 = *(const s8v*)((const char*)KBh + ln * 144 + 64 + grp * 16);
#pragma unroll
        for (int j = 0; j < 4; ++j) {
          float bb = ob[l * 64 + j * 16 + ln];
          f4v c = {bb, bb, bb, bb};
          c = MFMA32(a0, BT(48 + l * 8 + j), c);
          c = MFMA32(a1, BT(48 + l * 8 + 4 + j), c);
          v[j] += c;
        }
      }
      {
        const float* gp = ln1_g + l * 64;
        const float* bp = ln1_b + l * 64;
        float gg[4], bbv[4];
#pragma unroll
        for (int j = 0; j < 4; ++j) { gg[j] = gp[j * 16 + ln]; bbv[j] = bp[j * 16 + ln]; }
#pragma unroll
        for (int i = 0; i < 4; ++i) {
          float sm = v[0][i] + v[1][i] + v[2][i] + v[3][i];
          sm += __shfl_xor(sm, 1); sm += __shfl_xor(sm, 2);
          sm += __shfl_xor(sm, 4); sm += __shfl_xor(sm, 8);
          float mean = sm * 0.015625f;
          float q = 0.f;
#pragma unroll
          for (int j = 0; j < 4; ++j) { float d = v[j][i] - mean; q = fmaf(d, d, q); }
          q += __shfl_xor(q, 1); q += __shfl_xor(q, 2);
          q += __shfl_xor(q, 4); q += __shfl_xor(q, 8);
          float rs = rsqrtf(q * 0.015625f + 1e-5f);
#pragma unroll
          for (int j = 0; j < 4; ++j) {
            float nv = fmaf((v[j][i] - mean) * rs, gg[j], bbv[j]);
            v[j][i] = nv;
            HBh[(grp * 4 + i) * 72 + j * 16 + ln] = f2b(nv);
          }
        }
      }
      // ---- FF (two halves of 128 ff dims through F buffer) ----
      {
        f4v a2[4];
#pragma unroll
        for (int j = 0; j < 4; ++j) {
          float bb = ff2_b[l * 64 + j * 16 + ln];
          a2[j] = (f4v){bb, bb, bb, bb};
        }
        s8v ha0 = *(const s8v*)((const char*)HBh + ln * 144 + grp * 16);
        s8v ha1 = *(const s8v*)((const char*)HBh + ln * 144 + 64 + grp * 16);
#pragma unroll
        for (int half = 0; half < 2; ++half) {
#pragma unroll
          for (int j8 = 0; j8 < 8; ++j8) {
            int jt = half * 8 + j8;
            float bb = ff1_b[l * 256 + jt * 16 + ln];
            f4v c = {bb, bb, bb, bb};
            c = MFMA32(ha0, BT(64 + l * 32 + jt), c);
            c = MFMA32(ha1, BT(64 + l * 32 + 16 + jt), c);
#pragma unroll
            for (int i = 0; i < 4; ++i)
              Fh[(grp * 4 + i) * 136 + j8 * 16 + ln] = f2b(fmaxf(c[i], 0.f));
          }
#pragma unroll
          for (int kk2 = 0; kk2 < 4; ++kk2) {
            s8v fa = *(const s8v*)((const char*)Fh + ln * 272 + kk2 * 64 + grp * 16);
            int kkg = half * 4 + kk2;
            a2[0] = MFMA32(fa, BT(128 + l * 32 + kkg * 4 + 0), a2[0]);
            a2[1] = MFMA32(fa, BT(128 + l * 32 + kkg * 4 + 1), a2[1]);
            a2[2] = MFMA32(fa, BT(128 + l * 32 + kkg * 4 + 2), a2[2]);
            a2[3] = MFMA32(fa, BT(128 + l * 32 + kkg * 4 + 3), a2[3]);
          }
        }
#pragma unroll
        for (int j = 0; j < 4; ++j) v[j] += a2[j];
      }
      // ---- LN2 ----
      {
        const float* gp = ln2_g + l * 64;
        const float* bp = ln2_b + l * 64;
        float gg[4], bbv[4];
#pragma unroll
        for (int j = 0; j < 4; ++j) { gg[j] = gp[j * 16 + ln]; bbv[j] = bp[j * 16 + ln]; }
#pragma unroll
        for (int i = 0; i < 4; ++i) {
          float sm = v[0][i] + v[1][i] + v[2][i] + v[3][i];
          sm += __shfl_xor(sm, 1); sm += __shfl_xor(sm, 2);
          sm += __shfl_xor(sm, 4); sm += __shfl_xor(sm, 8);
          float mean = sm * 0.015625f;
          float q = 0.f;
#pragma unroll
          for (int j = 0; j < 4; ++j) { float d = v[j][i] - mean; q = fmaf(d, d, q); }
          q += __shfl_xor(q, 1); q += __shfl_xor(q, 2);
          q += __shfl_xor(q, 4); q += __shfl_xor(q, 8);
          float rs = rsqrtf(q * 0.015625f + 1e-5f);
#pragma unroll
          for (int j = 0; j < 4; ++j) {
            float nv = fmaf((v[j][i] - mean) * rs, gg[j], bbv[j]);
            v[j][i] = nv;
            HBh[(grp * 4 + i) * 72 + j * 16 + ln] = f2b(nv);
          }
        }
      }
    } // layer

    // ---- head: mean over t, dot w_out, sigmoid ----
    {
      float cs[4];
#pragma unroll
      for (int j = 0; j < 4; ++j) {
        float c0 = (grp < 3) ? (v[j][0] + v[j][1] + v[j][2] + v[j][3]) : 0.f;
        c0 += __shfl_xor(c0, 16);
        c0 += __shfl_xor(c0, 32);
        cs[j] = c0;
      }
      float dp = cs[0] * wo4[0] + cs[1] * wo4[1] + cs[2] * wo4[2] + cs[3] * wo4[3];
      dp += __shfl_xor(dp, 1);
      dp += __shfl_xor(dp, 2);
      dp += __shfl_xor(dp, 4);
      dp += __shfl_xor(dp, 8);
      if (lane == 0) {
        float logit = dp * (1.f / 12.f) + bo0;
        int hf = ((sp >> 4) << 4) | (s >> 4);
        int wf = ((sp & 15) << 4) | (s & 15);
        out[hf * 256 + wf] = 1.f / (1.f + expf(-logit));
      }
    }
  } // seq loop
#undef BT
}

extern "C" void kernel_launch(void* const* d_in, const int* in_sizes, int n_in,
                              void* d_out, int out_size, void* d_ws, size_t ws_size,
                              hipStream_t stream) {
  (void)in_sizes; (void)n_in; (void)out_size; (void)ws_size;
  wpack<<<48, 256, 0, stream>>>(
      (const float*)d_in[7],  (const float*)d_in[9],
      (const float*)d_in[13], (const float*)d_in[15], (unsigned int*)d_ws);
  prithvi_fused<<<256, 512, 0, stream>>>(
      (const float*)d_in[0],  (const float*)d_in[1],  (const float*)d_in[2],
      (const float*)d_in[3],  (const float*)d_in[4],  (const float*)d_in[5],
      (const float*)d_in[6],  (const float*)d_in[8],  (const float*)d_in[10],
      (const float*)d_in[11], (const float*)d_in[12], (const float*)d_in[14],
      (const float*)d_in[16], (const float*)d_in[17], (const float*)d_in[18],
      (const float*)d_in[19], (const float*)d_in[20], (const float*)d_ws,
      (float*)d_out);
}

// Round 8
// 1098.403 us; speedup vs baseline: 6.0700x; 1.3242x over previous
//
#include <hip/hip_runtime.h>
#include <math.h>

// R7: latency attack. (1) S^T trick: scores = mfma(A=K, B=Q) so the score
// C-frag IS the PV A-frag (P never touches LDS) and QKV's V C-frag IS the
// PV B-frag (V never touches LDS); softmax = in-lane + shfl_xor(16,32).
// (2) LDS 156KB -> 78KB (conv staged in two 24KB K-halves; F aliases Q/K,
// O aliases K) -> 2 blocks/CU = 4 waves/SIMD. Grid 512: block = 128 seqs
// of one cell; conv split by output channel (no duplicate FLOPs).

typedef __attribute__((ext_vector_type(8))) short s8v;
typedef __attribute__((ext_vector_type(4))) short s4v;
typedef __attribute__((ext_vector_type(4))) float f4v;
typedef __attribute__((ext_vector_type(4))) unsigned int u4v;

#define MFMA32(A, B, C) __builtin_amdgcn_mfma_f32_16x16x32_bf16((A), (B), (C), 0, 0, 0)
#define MFMA16(A, B, C) __builtin_amdgcn_mfma_f32_16x16x16bf16_1k((A), (B), (C), 0, 0, 0)

static __device__ __forceinline__ unsigned short f2b(float f) {
  unsigned u = __builtin_bit_cast(unsigned, f);
  u += 0x7fffu + ((u >> 16) & 1u);
  return (unsigned short)(u >> 16);
}
static __device__ __forceinline__ float b2f(unsigned short h) {
  return __builtin_bit_cast(float, ((unsigned)h) << 16);
}

// ---- prologue: pack weights into MFMA B-fragment order (bf16) ----
// tile t: lane l holds B[k = kk*32 + (l>>4)*8 + e][n = j*16 + (l&15)], e=0..7
// bases: qkv l*24 + kk*12 + j | ow 48 + l*8 + kk*4 + j
//        ff1 64 + l*32 + kk*16 + j | ff2 128 + l*32 + kkg*4 + j
__global__ __launch_bounds__(256) void wpack(
    const float* __restrict__ qkv_w, const float* __restrict__ ow,
    const float* __restrict__ ff1_w, const float* __restrict__ ff2_w,
    unsigned int* __restrict__ ws) {
  int gid = blockIdx.x * 256 + threadIdx.x;   // 0..12287
  int tIdx = gid >> 6, lane = gid & 63;
  int ln = lane & 15, grp = lane >> 4;
  const float* src;
  if (tIdx < 48) {
    int l = tIdx / 24, r = tIdx % 24, kk = r / 12, j = r % 12;
    src = qkv_w + l * 12288 + (j * 16 + ln) * 64 + kk * 32 + grp * 8;
  } else if (tIdx < 64) {
    int u = tIdx - 48, l = u / 8, r = u % 8, kk = r / 4, j = r % 4;
    src = ow + l * 4096 + (j * 16 + ln) * 64 + kk * 32 + grp * 8;
  } else if (tIdx < 128) {
    int u = tIdx - 64, l = u / 32, r = u % 32, kk = r / 16, j = r % 16;
    src = ff1_w + l * 16384 + (j * 16 + ln) * 64 + kk * 32 + grp * 8;
  } else {
    int u = tIdx - 128, l = u / 32, r = u % 32, kk = r / 4, j = r % 4;
    src = ff2_w + l * 16384 + (j * 16 + ln) * 256 + kk * 32 + grp * 8;
  }
  unsigned p[4];
#pragma unroll
  for (int e = 0; e < 4; ++e)
    p[e] = (unsigned)f2b(src[2 * e]) | ((unsigned)f2b(src[2 * e + 1]) << 16);
  u4v val = {p[0], p[1], p[2], p[3]};
  *(u4v*)(ws + (size_t)gid * 4) = val;
}

__global__ __launch_bounds__(512) void prithvi_fused(
    const float* __restrict__ x,     const float* __restrict__ conv_w,
    const float* __restrict__ bn_g,  const float* __restrict__ bn_b,
    const float* __restrict__ bn_m,  const float* __restrict__ bn_v,
    const float* __restrict__ w_in,  const float* __restrict__ qkv_b,
    const float* __restrict__ ob,    const float* __restrict__ ln1_g,
    const float* __restrict__ ln1_b, const float* __restrict__ ff1_b,
    const float* __restrict__ ff2_b, const float* __restrict__ ln2_g,
    const float* __restrict__ ln2_b, const float* __restrict__ w_out,
    const float* __restrict__ b_out, const float* __restrict__ ws,
    float* __restrict__ out)
{
  __shared__ __align__(16) float sbuf[6144];     // 24KB: xs K-half fp32; then g bf16 (12KB)
  __shared__ __align__(16) char WBuf[8][6912];   // per-wave: HB(2304)|QB(2304)|KB(2304); F aliases QB+KB

  const int blk = blockIdx.x, sp = blk >> 1, bh = blk & 1;
  const int tid = threadIdx.x, lane = tid & 63, wave = tid >> 6;

  // ---------------- conv: 1 output channel/thread, K staged in 2 halves ----
  {
    float acc[12];
#pragma unroll
    for (int t = 0; t < 12; ++t) acc[t] = 0.f;
    const int c_ = tid >> 7, jj = tid & 127;
    const int oc = c_ * 256 + bh * 128 + jj;
    const float* wrow = conv_w + (size_t)oc * 1024;
#pragma unroll 1
    for (int p = 0; p < 2; ++p) {
      for (int ch = tid; ch < 6144; ch += 512) {
        int e = ch / 12, t = ch - e * 12;
        sbuf[t * 512 + e] = x[(size_t)((p * 512 + e) * 12 + t) * 256 + sp];
      }
      __syncthreads();
      for (int eb = 0; eb < 512; eb += 4) {
        float4 w4 = *(const float4*)(wrow + p * 512 + eb);
#pragma unroll
        for (int t = 0; t < 12; ++t) {
          float4 xv = *(const float4*)&sbuf[t * 512 + eb];
          acc[t] = fmaf(xv.x, w4.x, acc[t]);
          acc[t] = fmaf(xv.y, w4.y, acc[t]);
          acc[t] = fmaf(xv.z, w4.z, acc[t]);
          acc[t] = fmaf(xv.w, w4.w, acc[t]);
        }
      }
      __syncthreads();
    }
    unsigned short* gW = (unsigned short*)sbuf;
    float sc0 = bn_g[oc] * rsqrtf(bn_v[oc] + 1e-5f);
    float sh0 = fmaf(-bn_m[oc], sc0, bn_b[oc]);
#pragma unroll
    for (int t = 0; t < 12; ++t) {
      float z = fmaf(acc[t], sc0, sh0);
      gW[(c_ * 128 + jj) * 12 + t] = f2b(0.5f * z * (1.f + erff(z * 0.70710678118654752f)));
    }
  }
  __syncthreads();   // g (bf16, 512 ch x 12) read-only from here

  // ---------------- phase 3 ----------------
  const int ln = lane & 15, grp = lane >> 4;
  char* Wb = &WBuf[wave][0];
  unsigned short* HBh = (unsigned short*)Wb;            // [16][72] h
  unsigned short* QBh = (unsigned short*)(Wb + 2304);   // Q
  unsigned short* KBh = (unsigned short*)(Wb + 4608);   // K, then O
  unsigned short* Fh  = (unsigned short*)(Wb + 2304);   // [16][136] h, aliases QB+KB
  const unsigned short* gB = (const unsigned short*)sbuf;
  const u4v* WS = (const u4v*)ws;
#define BT(T) __builtin_bit_cast(s8v, WS[(T) * 64 + lane])

  float pe[4][4], wic[4][4];
#pragma unroll
  for (int j = 0; j < 4; ++j) {
    int d = j * 16 + ln;
    float freq = expf(-(float)(d & ~1) * (9.210340371976184f / 64.f));
#pragma unroll
    for (int i = 0; i < 4; ++i) {
      float a = freq * (float)(grp * 4 + i);
      pe[i][j] = (d & 1) ? cosf(a) : sinf(a);
    }
#pragma unroll
    for (int c = 0; c < 4; ++c) wic[j][c] = w_in[d * 4 + c];
  }
  float wo4[4];
#pragma unroll
  for (int j = 0; j < 4; ++j) wo4[j] = w_out[j * 16 + ln];
  const float bo0 = b_out[0];

#pragma unroll 1
  for (int it = 0; it < 16; ++it) {
    const int sl = wave * 16 + it;      // local seq 0..127
    const int s  = bh * 128 + sl;       // global subpixel
    f4v v[4];

    // ---- h0 (fp32 C-frag in regs) + HB bf16 ----
    {
      int tb = (grp < 3) ? grp * 4 : 0;
#pragma unroll
      for (int i = 0; i < 4; ++i) {
        float g0 = b2f(gB[(0 * 128 + sl) * 12 + tb + i]);
        float g1 = b2f(gB[(1 * 128 + sl) * 12 + tb + i]);
        float g2 = b2f(gB[(2 * 128 + sl) * 12 + tb + i]);
        float g3 = b2f(gB[(3 * 128 + sl) * 12 + tb + i]);
#pragma unroll
        for (int j = 0; j < 4; ++j)
          v[j][i] = fmaf(g0, wic[j][0], fmaf(g1, wic[j][1],
                    fmaf(g2, wic[j][2], fmaf(g3, wic[j][3], pe[i][j]))));
      }
#pragma unroll
      for (int i = 0; i < 4; ++i)
#pragma unroll
        for (int j = 0; j < 4; ++j)
          HBh[(grp * 4 + i) * 72 + j * 16 + ln] = f2b(v[j][i]);
    }

#pragma unroll 1
    for (int l = 0; l < 2; ++l) {
      s4v vfrag[4];
      // ---- QKV: Q,K -> LDS (need transpose); V -> regs (C-frag == PV B-frag) ----
      {
        s8v a0 = *(const s8v*)((const char*)HBh + ln * 144 + grp * 16);
        s8v a1 = *(const s8v*)((const char*)HBh + ln * 144 + 64 + grp * 16);
#pragma unroll
        for (int j = 0; j < 12; ++j) {
          float bb = qkv_b[l * 192 + j * 16 + ln];
          f4v c = {bb, bb, bb, bb};
          c = MFMA32(a0, BT(l * 24 + j), c);
          c = MFMA32(a1, BT(l * 24 + 12 + j), c);
          if (j < 4) {
#pragma unroll
            for (int i = 0; i < 4; ++i)
              QBh[(grp * 4 + i) * 72 + j * 16 + ln] = f2b(c[i]);
          } else if (j < 8) {
#pragma unroll
            for (int i = 0; i < 4; ++i)
              KBh[(grp * 4 + i) * 72 + (j - 4) * 16 + ln] = f2b(c[i]);
          } else {
            s4v pv;
            pv[0] = (short)f2b(c[0]); pv[1] = (short)f2b(c[1]);
            pv[2] = (short)f2b(c[2]); pv[3] = (short)f2b(c[3]);
            vfrag[j - 8] = pv;
          }
        }
      }
      // ---- attention: S^T = mfma(K, Q); softmax over rows (in-lane + grp shfl);
      //      P C-frag == PV A-frag; O -> KB (K cols dead per head) ----
      {
        const f4v z4 = {0.f, 0.f, 0.f, 0.f};
#pragma unroll
        for (int hh = 0; hh < 4; ++hh) {
          s4v aK = *(const s4v*)((const char*)KBh + ln * 144 + hh * 32 + grp * 8);
          s4v bQ = *(const s4v*)((const char*)QBh + ln * 144 + hh * 32 + grp * 8);
          f4v sc = MFMA16(aK, bQ, z4);   // lane: score(q=ln, k=grp*4+i)
          float si0, si1, si2, si3;
          if (grp == 3) { si0 = si1 = si2 = si3 = -1e30f; }
          else { si0 = sc[0] * 0.25f; si1 = sc[1] * 0.25f;
                 si2 = sc[2] * 0.25f; si3 = sc[3] * 0.25f; }
          float m = fmaxf(fmaxf(si0, si1), fmaxf(si2, si3));
          m = fmaxf(m, __shfl_xor(m, 16));
          m = fmaxf(m, __shfl_xor(m, 32));
          float e0 = expf(si0 - m), e1 = expf(si1 - m);
          float e2 = expf(si2 - m), e3 = expf(si3 - m);
          float sm = (e0 + e1) + (e2 + e3);
          sm += __shfl_xor(sm, 16);
          sm += __shfl_xor(sm, 32);
          float inv = 1.f / sm;
          s4v aP;
          aP[0] = (short)f2b(e0 * inv); aP[1] = (short)f2b(e1 * inv);
          aP[2] = (short)f2b(e2 * inv); aP[3] = (short)f2b(e3 * inv);
          f4v o4 = MFMA16(aP, vfrag[hh], z4);   // O head-hh C-frag
#pragma unroll
          for (int i = 0; i < 4; ++i)
            KBh[(grp * 4 + i) * 72 + hh * 16 + ln] = f2b(o4[i]);
        }
      }
      // ---- O-proj + residual ----
      {
        s8v a0 = *(const s8v*)((const char*)KBh + ln * 144 + grp * 16);
        s8v a1 = *(const s8v*)((const char*)KBh + ln * 144 + 64 + grp * 16);
#pragma unroll
        for (int j = 0; j < 4; ++j) {
          float bb = ob[l * 64 + j * 16 + ln];
          f4v c = {bb, bb, bb, bb};
          c = MFMA32(a0, BT(48 + l * 8 + j), c);
          c = MFMA32(a1, BT(48 + l * 8 + 4 + j), c);
          v[j] += c;
        }
      }
      // ---- LN1 -> HB ----
      {
        const float* gp = ln1_g + l * 64;
        const float* bp = ln1_b + l * 64;
        float gg[4], bbv[4];
#pragma unroll
        for (int j = 0; j < 4; ++j) { gg[j] = gp[j * 16 + ln]; bbv[j] = bp[j * 16 + ln]; }
#pragma unroll
        for (int i = 0; i < 4; ++i) {
          float sm = v[0][i] + v[1][i] + v[2][i] + v[3][i];
          sm += __shfl_xor(sm, 1); sm += __shfl_xor(sm, 2);
          sm += __shfl_xor(sm, 4); sm += __shfl_xor(sm, 8);
          float mean = sm * 0.015625f;
          float q = 0.f;
#pragma unroll
          for (int j = 0; j < 4; ++j) { float d = v[j][i] - mean; q = fmaf(d, d, q); }
          q += __shfl_xor(q, 1); q += __shfl_xor(q, 2);
          q += __shfl_xor(q, 4); q += __shfl_xor(q, 8);
          float rs = rsqrtf(q * 0.015625f + 1e-5f);
#pragma unroll
          for (int j = 0; j < 4; ++j) {
            float nv = fmaf((v[j][i] - mean) * rs, gg[j], bbv[j]);
            v[j][i] = nv;
            HBh[(grp * 4 + i) * 72 + j * 16 + ln] = f2b(nv);
          }
        }
      }
      // ---- FF (F aliases QB+KB; Q,K,O dead) ----
      {
        f4v a2[4];
#pragma unroll
        for (int j = 0; j < 4; ++j) {
          float bb = ff2_b[l * 64 + j * 16 + ln];
          a2[j] = (f4v){bb, bb, bb, bb};
        }
        s8v ha0 = *(const s8v*)((const char*)HBh + ln * 144 + grp * 16);
        s8v ha1 = *(const s8v*)((const char*)HBh + ln * 144 + 64 + grp * 16);
#pragma unroll
        for (int fh = 0; fh < 2; ++fh) {
#pragma unroll
          for (int j8 = 0; j8 < 8; ++j8) {
            int jt = fh * 8 + j8;
            float bb = ff1_b[l * 256 + jt * 16 + ln];
            f4v c = {bb, bb, bb, bb};
            c = MFMA32(ha0, BT(64 + l * 32 + jt), c);
            c = MFMA32(ha1, BT(64 + l * 32 + 16 + jt), c);
#pragma unroll
            for (int i = 0; i < 4; ++i)
              Fh[(grp * 4 + i) * 136 + j8 * 16 + ln] = f2b(fmaxf(c[i], 0.f));
          }
#pragma unroll
          for (int kk2 = 0; kk2 < 4; ++kk2) {
            s8v fa = *(const s8v*)((const char*)Fh + ln * 272 + kk2 * 64 + grp * 16);
            int kkg = fh * 4 + kk2;
            a2[0] = MFMA32(fa, BT(128 + l * 32 + kkg * 4 + 0), a2[0]);
            a2[1] = MFMA32(fa, BT(128 + l * 32 + kkg * 4 + 1), a2[1]);
            a2[2] = MFMA32(fa, BT(128 + l * 32 + kkg * 4 + 2), a2[2]);
            a2[3] = MFMA32(fa, BT(128 + l * 32 + kkg * 4 + 3), a2[3]);
          }
        }
#pragma unroll
        for (int j = 0; j < 4; ++j) v[j] += a2[j];
      }
      // ---- LN2 -> HB ----
      {
        const float* gp = ln2_g + l * 64;
        const float* bp = ln2_b + l * 64;
        float gg[4], bbv[4];
#pragma unroll
        for (int j = 0; j < 4; ++j) { gg[j] = gp[j * 16 + ln]; bbv[j] = bp[j * 16 + ln]; }
#pragma unroll
        for (int i = 0; i < 4; ++i) {
          float sm = v[0][i] + v[1][i] + v[2][i] + v[3][i];
          sm += __shfl_xor(sm, 1); sm += __shfl_xor(sm, 2);
          sm += __shfl_xor(sm, 4); sm += __shfl_xor(sm, 8);
          float mean = sm * 0.015625f;
          float q = 0.f;
#pragma unroll
          for (int j = 0; j < 4; ++j) { float d = v[j][i] - mean; q = fmaf(d, d, q); }
          q += __shfl_xor(q, 1); q += __shfl_xor(q, 2);
          q += __shfl_xor(q, 4); q += __shfl_xor(q, 8);
          float rs = rsqrtf(q * 0.015625f + 1e-5f);
#pragma unroll
          for (int j = 0; j < 4; ++j) {
            float nv = fmaf((v[j][i] - mean) * rs, gg[j], bbv[j]);
            v[j][i] = nv;
            HBh[(grp * 4 + i) * 72 + j * 16 + ln] = f2b(nv);
          }
        }
      }
    } // layer

    // ---- head: mean over t, dot w_out, sigmoid ----
    {
      float cs[4];
#pragma unroll
      for (int j = 0; j < 4; ++j) {
        float c0 = (grp < 3) ? (v[j][0] + v[j][1] + v[j][2] + v[j][3]) : 0.f;
        c0 += __shfl_xor(c0, 16);
        c0 += __shfl_xor(c0, 32);
        cs[j] = c0;
      }
      float dp = cs[0] * wo4[0] + cs[1] * wo4[1] + cs[2] * wo4[2] + cs[3] * wo4[3];
      dp += __shfl_xor(dp, 1);
      dp += __shfl_xor(dp, 2);
      dp += __shfl_xor(dp, 4);
      dp += __shfl_xor(dp, 8);
      if (lane == 0) {
        float logit = dp * (1.f / 12.f) + bo0;
        int hf = ((sp >> 4) << 4) | (s >> 4);
        int wf = ((sp & 15) << 4) | (s & 15);
        out[hf * 256 + wf] = 1.f / (1.f + expf(-logit));
      }
    }
  } // seq loop
#undef BT
}

extern "C" void kernel_launch(void* const* d_in, const int* in_sizes, int n_in,
                              void* d_out, int out_size, void* d_ws, size_t ws_size,
                              hipStream_t stream) {
  (void)in_sizes; (void)n_in; (void)out_size; (void)ws_size;
  wpack<<<48, 256, 0, stream>>>(
      (const float*)d_in[7],  (const float*)d_in[9],
      (const float*)d_in[13], (const float*)d_in[15], (unsigned int*)d_ws);
  prithvi_fused<<<512, 512, 0, stream>>>(
      (const float*)d_in[0],  (const float*)d_in[1],  (const float*)d_in[2],
      (const float*)d_in[3],  (const float*)d_in[4],  (const float*)d_in[5],
      (const float*)d_in[6],  (const float*)d_in[8],  (const float*)d_in[10],
      (const float*)d_in[11], (const float*)d_in[12], (const float*)d_in[14],
      (const float*)d_in[16], (const float*)d_in[17], (const float*)d_in[18],
      (const float*)d_in[19], (const float*)d_in[20], (const float*)d_ws,
      (float*)d_out);
}

// Round 9
// 922.629 us; speedup vs baseline: 7.2264x; 1.1905x over previous
//
#include <hip/hip_runtime.h>
#include <math.h>

// R8: 2-seq-per-wave interleave (intra-wave ILP, since 2nd block/CU refused
// to co-reside in R7). 256 blocks x 512 thr, 1 block/CU, 8 waves; each wave
// runs 32 seqs as 16 iterations of 2 interleaved chains. Biases+accums for
// O-proj/FF2 folded into residual v-frags (VGPR control, ~110 live < 128).
// LDS rows padded: H/Q/K stride 76 ushorts (152B -> grp rows on banks
// {0,24,16,8}, conflict-free stores), F stride 140.

typedef __attribute__((ext_vector_type(8))) short s8v;
typedef __attribute__((ext_vector_type(4))) short s4v;
typedef __attribute__((ext_vector_type(4))) float f4v;
typedef __attribute__((ext_vector_type(4))) unsigned int u4v;

#define MFMA32(A, B, C) __builtin_amdgcn_mfma_f32_16x16x32_bf16((A), (B), (C), 0, 0, 0)
#define MFMA16(A, B, C) __builtin_amdgcn_mfma_f32_16x16x16bf16_1k((A), (B), (C), 0, 0, 0)
#define LGKM0 asm volatile("s_waitcnt lgkmcnt(0)" ::: "memory")

static __device__ __forceinline__ unsigned short f2b(float f) {
  unsigned u = __builtin_bit_cast(unsigned, f);
  u += 0x7fffu + ((u >> 16) & 1u);
  return (unsigned short)(u >> 16);
}
static __device__ __forceinline__ float b2f(unsigned short h) {
  return __builtin_bit_cast(float, ((unsigned)h) << 16);
}

// ---- prologue: pack weights into MFMA B-fragment order (bf16) ----
// tile t: lane l holds B[k = kk*32 + (l>>4)*8 + e][n = j*16 + (l&15)], e=0..7
// bases: qkv l*24 + kk*12 + j | ow 48 + l*8 + kk*4 + j
//        ff1 64 + l*32 + kk*16 + j | ff2 128 + l*32 + kkg*4 + j
__global__ __launch_bounds__(256) void wpack(
    const float* __restrict__ qkv_w, const float* __restrict__ ow,
    const float* __restrict__ ff1_w, const float* __restrict__ ff2_w,
    unsigned int* __restrict__ ws) {
  int gid = blockIdx.x * 256 + threadIdx.x;   // 0..12287
  int tIdx = gid >> 6, lane = gid & 63;
  int ln = lane & 15, grp = lane >> 4;
  const float* src;
  if (tIdx < 48) {
    int l = tIdx / 24, r = tIdx % 24, kk = r / 12, j = r % 12;
    src = qkv_w + l * 12288 + (j * 16 + ln) * 64 + kk * 32 + grp * 8;
  } else if (tIdx < 64) {
    int u = tIdx - 48, l = u / 8, r = u % 8, kk = r / 4, j = r % 4;
    src = ow + l * 4096 + (j * 16 + ln) * 64 + kk * 32 + grp * 8;
  } else if (tIdx < 128) {
    int u = tIdx - 64, l = u / 32, r = u % 32, kk = r / 16, j = r % 16;
    src = ff1_w + l * 16384 + (j * 16 + ln) * 64 + kk * 32 + grp * 8;
  } else {
    int u = tIdx - 128, l = u / 32, r = u % 32, kk = r / 4, j = r % 4;
    src = ff2_w + l * 16384 + (j * 16 + ln) * 256 + kk * 32 + grp * 8;
  }
  unsigned p[4];
#pragma unroll
  for (int e = 0; e < 4; ++e)
    p[e] = (unsigned)f2b(src[2 * e]) | ((unsigned)f2b(src[2 * e + 1]) << 16);
  u4v val = {p[0], p[1], p[2], p[3]};
  *(u4v*)(ws + (size_t)gid * 4) = val;
}

__global__ __launch_bounds__(512) void prithvi_fused(
    const float* __restrict__ x,     const float* __restrict__ conv_w,
    const float* __restrict__ bn_g,  const float* __restrict__ bn_b,
    const float* __restrict__ bn_m,  const float* __restrict__ bn_v,
    const float* __restrict__ w_in,  const float* __restrict__ qkv_b,
    const float* __restrict__ ob,    const float* __restrict__ ln1_g,
    const float* __restrict__ ln1_b, const float* __restrict__ ff1_b,
    const float* __restrict__ ff2_b, const float* __restrict__ ln2_g,
    const float* __restrict__ ln2_b, const float* __restrict__ w_out,
    const float* __restrict__ b_out, const float* __restrict__ ws,
    float* __restrict__ out)
{
  __shared__ __align__(16) float sbuf[6144];        // 24KB: xs K-half fp32; then g bf16 (1024ch x 12)
  __shared__ __align__(16) char WBuf[8][2][7296];   // per wave, per seq-slot: HB|QB|KB (F aliases QB+KB)

  const int sp = blockIdx.x, tid = threadIdx.x;
  const int lane = tid & 63, wave = tid >> 6;

  // ---------------- conv: 2 output channels/thread, x staged in 2 K-halves ----
  {
    float acc0[12], acc1[12];
#pragma unroll
    for (int t = 0; t < 12; ++t) { acc0[t] = 0.f; acc1[t] = 0.f; }
    const float* w0p = conv_w + (size_t)tid * 1024;
    const float* w1p = conv_w + (size_t)(tid + 512) * 1024;
#pragma unroll 1
    for (int p = 0; p < 2; ++p) {
      for (int ch = tid; ch < 6144; ch += 512) {
        int e = ch / 12, t = ch - e * 12;
        sbuf[t * 512 + e] = x[(size_t)((p * 512 + e) * 12 + t) * 256 + sp];
      }
      __syncthreads();
      for (int eb = 0; eb < 512; eb += 4) {
        float4 wa = *(const float4*)(w0p + p * 512 + eb);
        float4 wb = *(const float4*)(w1p + p * 512 + eb);
#pragma unroll
        for (int t = 0; t < 12; ++t) {
          float4 xv = *(const float4*)&sbuf[t * 512 + eb];
          acc0[t] = fmaf(xv.x, wa.x, acc0[t]);
          acc0[t] = fmaf(xv.y, wa.y, acc0[t]);
          acc0[t] = fmaf(xv.z, wa.z, acc0[t]);
          acc0[t] = fmaf(xv.w, wa.w, acc0[t]);
          acc1[t] = fmaf(xv.x, wb.x, acc1[t]);
          acc1[t] = fmaf(xv.y, wb.y, acc1[t]);
          acc1[t] = fmaf(xv.z, wb.z, acc1[t]);
          acc1[t] = fmaf(xv.w, wb.w, acc1[t]);
        }
      }
      __syncthreads();
    }
    unsigned short* gW = (unsigned short*)sbuf;
    {
      float sc0 = bn_g[tid] * rsqrtf(bn_v[tid] + 1e-5f);
      float sh0 = fmaf(-bn_m[tid], sc0, bn_b[tid]);
#pragma unroll
      for (int t = 0; t < 12; ++t) {
        float z = fmaf(acc0[t], sc0, sh0);
        gW[tid * 12 + t] = f2b(0.5f * z * (1.f + erff(z * 0.70710678118654752f)));
      }
      int oc = tid + 512;
      float sc1 = bn_g[oc] * rsqrtf(bn_v[oc] + 1e-5f);
      float sh1 = fmaf(-bn_m[oc], sc1, bn_b[oc]);
#pragma unroll
      for (int t = 0; t < 12; ++t) {
        float z = fmaf(acc1[t], sc1, sh1);
        gW[oc * 12 + t] = f2b(0.5f * z * (1.f + erff(z * 0.70710678118654752f)));
      }
    }
  }
  __syncthreads();   // g (bf16, [1024][12]) read-only from here

  // ---------------- phase 3: 2 seqs in flight per wave ----------------
  const int ln = lane & 15, grp = lane >> 4;
  unsigned short* HB[2] = {(unsigned short*)&WBuf[wave][0][0],
                           (unsigned short*)&WBuf[wave][1][0]};
  unsigned short* QB[2] = {(unsigned short*)(&WBuf[wave][0][0] + 2432),
                           (unsigned short*)(&WBuf[wave][1][0] + 2432)};
  unsigned short* KB[2] = {(unsigned short*)(&WBuf[wave][0][0] + 4864),
                           (unsigned short*)(&WBuf[wave][1][0] + 4864)};
  unsigned short* FB[2] = {(unsigned short*)(&WBuf[wave][0][0] + 2432),
                           (unsigned short*)(&WBuf[wave][1][0] + 2432)};
  const unsigned short* gB = (const unsigned short*)sbuf;
  const u4v* WS = (const u4v*)ws;
#define BT(T) __builtin_bit_cast(s8v, WS[(T) * 64 + lane])

  float pe[4][4], wic[4][4];
#pragma unroll
  for (int j = 0; j < 4; ++j) {
    int d = j * 16 + ln;
    float freq = expf(-(float)(d & ~1) * (9.210340371976184f / 64.f));
#pragma unroll
    for (int i = 0; i < 4; ++i) {
      float a = freq * (float)(grp * 4 + i);
      pe[i][j] = (d & 1) ? cosf(a) : sinf(a);
    }
#pragma unroll
    for (int c = 0; c < 4; ++c) wic[j][c] = w_in[d * 4 + c];
  }
  float wo4[4];
#pragma unroll
  for (int j = 0; j < 4; ++j) wo4[j] = w_out[j * 16 + ln];
  const float bo0 = b_out[0];

#pragma unroll 1
  for (int it = 0; it < 16; ++it) {
    const int s0 = wave * 32 + it * 2;
    f4v v[2][4];

    // ---- h0 (fp32 C-frag) -> HB bf16, both seqs ----
    {
      int tb = (grp < 3) ? grp * 4 : 0;
#pragma unroll
      for (int u = 0; u < 2; ++u) {
        const int s = s0 + u;
#pragma unroll
        for (int i = 0; i < 4; ++i) {
          float g0 = b2f(gB[        s * 12 + tb + i]);
          float g1 = b2f(gB[3072 +  s * 12 + tb + i]);
          float g2 = b2f(gB[6144 +  s * 12 + tb + i]);
          float g3 = b2f(gB[9216 +  s * 12 + tb + i]);
#pragma unroll
          for (int j = 0; j < 4; ++j)
            v[u][j][i] = fmaf(g0, wic[j][0], fmaf(g1, wic[j][1],
                         fmaf(g2, wic[j][2], fmaf(g3, wic[j][3], pe[i][j]))));
        }
#pragma unroll
        for (int i = 0; i < 4; ++i)
#pragma unroll
          for (int j = 0; j < 4; ++j)
            HB[u][(grp * 4 + i) * 76 + j * 16 + ln] = f2b(v[u][j][i]);
      }
      LGKM0;
    }

#pragma unroll 1
    for (int l = 0; l < 2; ++l) {
      s4v vfrag[2][4];
      // ---- QKV: Q,K -> LDS; V -> regs (C-frag == PV B-frag) ----
      {
        s8v a0[2], a1[2];
#pragma unroll
        for (int u = 0; u < 2; ++u) {
          a0[u] = *(const s8v*)((const char*)HB[u] + ln * 152 + grp * 16);
          a1[u] = *(const s8v*)((const char*)HB[u] + ln * 152 + 64 + grp * 16);
        }
#pragma unroll
        for (int j = 0; j < 12; ++j) {
          float bb = qkv_b[l * 192 + j * 16 + ln];
#pragma unroll
          for (int u = 0; u < 2; ++u) {
            f4v c = {bb, bb, bb, bb};
            c = MFMA32(a0[u], BT(l * 24 + j), c);
            c = MFMA32(a1[u], BT(l * 24 + 12 + j), c);
            if (j < 4) {
#pragma unroll
              for (int i = 0; i < 4; ++i)
                QB[u][(grp * 4 + i) * 76 + j * 16 + ln] = f2b(c[i]);
            } else if (j < 8) {
#pragma unroll
              for (int i = 0; i < 4; ++i)
                KB[u][(grp * 4 + i) * 76 + (j - 4) * 16 + ln] = f2b(c[i]);
            } else {
              s4v pv;
              pv[0] = (short)f2b(c[0]); pv[1] = (short)f2b(c[1]);
              pv[2] = (short)f2b(c[2]); pv[3] = (short)f2b(c[3]);
              vfrag[u][j - 8] = pv;
            }
          }
        }
        LGKM0;
      }
      // ---- attention: S^T = mfma(K,Q); P C-frag == PV A-frag; O -> KB ----
      {
        const f4v z4 = {0.f, 0.f, 0.f, 0.f};
#pragma unroll
        for (int hh = 0; hh < 4; ++hh) {
#pragma unroll
          for (int u = 0; u < 2; ++u) {
            s4v aK = *(const s4v*)((const char*)KB[u] + ln * 152 + hh * 32 + grp * 8);
            s4v bQ = *(const s4v*)((const char*)QB[u] + ln * 152 + hh * 32 + grp * 8);
            f4v sc = MFMA16(aK, bQ, z4);   // lane: score(q=ln, k=grp*4+i)
            float si0, si1, si2, si3;
            if (grp == 3) { si0 = si1 = si2 = si3 = -1e30f; }
            else { si0 = sc[0] * 0.25f; si1 = sc[1] * 0.25f;
                   si2 = sc[2] * 0.25f; si3 = sc[3] * 0.25f; }
            float m = fmaxf(fmaxf(si0, si1), fmaxf(si2, si3));
            m = fmaxf(m, __shfl_xor(m, 16));
            m = fmaxf(m, __shfl_xor(m, 32));
            float e0 = expf(si0 - m), e1 = expf(si1 - m);
            float e2 = expf(si2 - m), e3 = expf(si3 - m);
            float sm = (e0 + e1) + (e2 + e3);
            sm += __shfl_xor(sm, 16);
            sm += __shfl_xor(sm, 32);
            float inv = 1.f / sm;
            s4v aP;
            aP[0] = (short)f2b(e0 * inv); aP[1] = (short)f2b(e1 * inv);
            aP[2] = (short)f2b(e2 * inv); aP[3] = (short)f2b(e3 * inv);
            f4v o4 = MFMA16(aP, vfrag[u][hh], z4);
#pragma unroll
            for (int i = 0; i < 4; ++i)
              KB[u][(grp * 4 + i) * 76 + hh * 16 + ln] = f2b(o4[i]);
          }
        }
        LGKM0;
      }
      // ---- O-proj + bias folded into residual v ----
      {
        s8v a0[2], a1[2];
#pragma unroll
        for (int u = 0; u < 2; ++u) {
          a0[u] = *(const s8v*)((const char*)KB[u] + ln * 152 + grp * 16);
          a1[u] = *(const s8v*)((const char*)KB[u] + ln * 152 + 64 + grp * 16);
        }
#pragma unroll
        for (int j = 0; j < 4; ++j) {
          float bb = ob[l * 64 + j * 16 + ln];
          f4v bb4 = {bb, bb, bb, bb};
#pragma unroll
          for (int u = 0; u < 2; ++u) {
            v[u][j] += bb4;
            v[u][j] = MFMA32(a0[u], BT(48 + l * 8 + j), v[u][j]);
            v[u][j] = MFMA32(a1[u], BT(48 + l * 8 + 4 + j), v[u][j]);
          }
        }
      }
      // ---- LN1 -> HB ----
      {
        const float* gp = ln1_g + l * 64;
        const float* bp = ln1_b + l * 64;
        float gg[4], bbv[4];
#pragma unroll
        for (int j = 0; j < 4; ++j) { gg[j] = gp[j * 16 + ln]; bbv[j] = bp[j * 16 + ln]; }
#pragma unroll
        for (int i = 0; i < 4; ++i) {
#pragma unroll
          for (int u = 0; u < 2; ++u) {
            float sm = v[u][0][i] + v[u][1][i] + v[u][2][i] + v[u][3][i];
            sm += __shfl_xor(sm, 1); sm += __shfl_xor(sm, 2);
            sm += __shfl_xor(sm, 4); sm += __shfl_xor(sm, 8);
            float mean = sm * 0.015625f;
            float q = 0.f;
#pragma unroll
            for (int j = 0; j < 4; ++j) { float d = v[u][j][i] - mean; q = fmaf(d, d, q); }
            q += __shfl_xor(q, 1); q += __shfl_xor(q, 2);
            q += __shfl_xor(q, 4); q += __shfl_xor(q, 8);
            float rs = rsqrtf(q * 0.015625f + 1e-5f);
#pragma unroll
            for (int j = 0; j < 4; ++j) {
              float nv = fmaf((v[u][j][i] - mean) * rs, gg[j], bbv[j]);
              v[u][j][i] = nv;
              HB[u][(grp * 4 + i) * 76 + j * 16 + ln] = f2b(nv);
            }
          }
        }
        LGKM0;
      }
      // ---- FF (F aliases QB+KB); FF2 bias + accum folded into v ----
      {
        s8v ha0[2], ha1[2];
#pragma unroll
        for (int u = 0; u < 2; ++u) {
          ha0[u] = *(const s8v*)((const char*)HB[u] + ln * 152 + grp * 16);
          ha1[u] = *(const s8v*)((const char*)HB[u] + ln * 152 + 64 + grp * 16);
        }
#pragma unroll
        for (int j = 0; j < 4; ++j) {
          float bb = ff2_b[l * 64 + j * 16 + ln];
          f4v bb4 = {bb, bb, bb, bb};
#pragma unroll
          for (int u = 0; u < 2; ++u) v[u][j] += bb4;
        }
#pragma unroll
        for (int fh = 0; fh < 2; ++fh) {
#pragma unroll
          for (int j8 = 0; j8 < 8; ++j8) {
            int jt = fh * 8 + j8;
            float bb = ff1_b[l * 256 + jt * 16 + ln];
#pragma unroll
            for (int u = 0; u < 2; ++u) {
              f4v c = {bb, bb, bb, bb};
              c = MFMA32(ha0[u], BT(64 + l * 32 + jt), c);
              c = MFMA32(ha1[u], BT(64 + l * 32 + 16 + jt), c);
#pragma unroll
              for (int i = 0; i < 4; ++i)
                FB[u][(grp * 4 + i) * 140 + j8 * 16 + ln] = f2b(fmaxf(c[i], 0.f));
            }
          }
          LGKM0;
#pragma unroll
          for (int kk2 = 0; kk2 < 4; ++kk2) {
            int kkg = fh * 4 + kk2;
#pragma unroll
            for (int u = 0; u < 2; ++u) {
              s8v fa = *(const s8v*)((const char*)FB[u] + ln * 280 + kk2 * 64 + grp * 16);
              v[u][0] = MFMA32(fa, BT(128 + l * 32 + kkg * 4 + 0), v[u][0]);
              v[u][1] = MFMA32(fa, BT(128 + l * 32 + kkg * 4 + 1), v[u][1]);
              v[u][2] = MFMA32(fa, BT(128 + l * 32 + kkg * 4 + 2), v[u][2]);
              v[u][3] = MFMA32(fa, BT(128 + l * 32 + kkg * 4 + 3), v[u][3]);
            }
          }
        }
      }
      // ---- LN2 (store HB only if another layer follows) ----
      {
        const float* gp = ln2_g + l * 64;
        const float* bp = ln2_b + l * 64;
        float gg[4], bbv[4];
#pragma unroll
        for (int j = 0; j < 4; ++j) { gg[j] = gp[j * 16 + ln]; bbv[j] = bp[j * 16 + ln]; }
#pragma unroll
        for (int i = 0; i < 4; ++i) {
#pragma unroll
          for (int u = 0; u < 2; ++u) {
            float sm = v[u][0][i] + v[u][1][i] + v[u][2][i] + v[u][3][i];
            sm += __shfl_xor(sm, 1); sm += __shfl_xor(sm, 2);
            sm += __shfl_xor(sm, 4); sm += __shfl_xor(sm, 8);
            float mean = sm * 0.015625f;
            float q = 0.f;
#pragma unroll
            for (int j = 0; j < 4; ++j) { float d = v[u][j][i] - mean; q = fmaf(d, d, q); }
            q += __shfl_xor(q, 1); q += __shfl_xor(q, 2);
            q += __shfl_xor(q, 4); q += __shfl_xor(q, 8);
            float rs = rsqrtf(q * 0.015625f + 1e-5f);
#pragma unroll
            for (int j = 0; j < 4; ++j) {
              float nv = fmaf((v[u][j][i] - mean) * rs, gg[j], bbv[j]);
              v[u][j][i] = nv;
              if (l == 0) HB[u][(grp * 4 + i) * 76 + j * 16 + ln] = f2b(nv);
            }
          }
        }
        if (l == 0) LGKM0;
      }
    } // layer

    // ---- head: mean over t, dot w_out, sigmoid (both seqs) ----
#pragma unroll
    for (int u = 0; u < 2; ++u) {
      float cs[4];
#pragma unroll
      for (int j = 0; j < 4; ++j) {
        float c0 = (grp < 3) ? (v[u][j][0] + v[u][j][1] + v[u][j][2] + v[u][j][3]) : 0.f;
        c0 += __shfl_xor(c0, 16);
        c0 += __shfl_xor(c0, 32);
        cs[j] = c0;
      }
      float dp = cs[0] * wo4[0] + cs[1] * wo4[1] + cs[2] * wo4[2] + cs[3] * wo4[3];
      dp += __shfl_xor(dp, 1);
      dp += __shfl_xor(dp, 2);
      dp += __shfl_xor(dp, 4);
      dp += __shfl_xor(dp, 8);
      if (lane == 0) {
        const int s = s0 + u;
        float logit = dp * (1.f / 12.f) + bo0;
        int hf = ((sp >> 4) << 4) | (s >> 4);
        int wf = ((sp & 15) << 4) | (s & 15);
        out[hf * 256 + wf] = 1.f / (1.f + expf(-logit));
      }
    }
  } // seq loop
#undef BT
}

extern "C" void kernel_launch(void* const* d_in, const int* in_sizes, int n_in,
                              void* d_out, int out_size, void* d_ws, size_t ws_size,
                              hipStream_t stream) {
  (void)in_sizes; (void)n_in; (void)out_size; (void)ws_size;
  wpack<<<48, 256, 0, stream>>>(
      (const float*)d_in[7],  (const float*)d_in[9],
      (const float*)d_in[13], (const float*)d_in[15], (unsigned int*)d_ws);
  prithvi_fused<<<256, 512, 0, stream>>>(
      (const float*)d_in[0],  (const float*)d_in[1],  (const float*)d_in[2],
      (const float*)d_in[3],  (const float*)d_in[4],  (const float*)d_in[5],
      (const float*)d_in[6],  (const float*)d_in[8],  (const float*)d_in[10],
      (const float*)d_in[11], (const float*)d_in[12], (const float*)d_in[14],
      (const float*)d_in[16], (const float*)d_in[17], (const float*)d_in[18],
      (const float*)d_in[19], (const float*)d_in[20], (const float*)d_ws,
      (float*)d_out);
}

// Round 11
// 845.843 us; speedup vs baseline: 7.8824x; 1.0908x over previous
//
#include <hip/hip_runtime.h>
#include <math.h>

// R9 (resubmitted R10 after container failure), on R8's 2-seq interleave:
//  1) f2b = native __bf16 cast -> compiler emits v_cvt_pk_bf16_f32 pairs
//     (was ~3-op manual RNE per value, ~370/seq).
//  2) All explicit lgkmcnt(0) drains removed in phase 3: wave-private LDS,
//     DS ops in-order per wave, compiler inserts precise waits for reads.
//  3) Softmax without max-subtract (scores finite & small; identical math),
//     __expf, pad lanes -> e=0 directly: kills fmax tree + 2 shfls/head.

typedef __attribute__((ext_vector_type(8))) short s8v;
typedef __attribute__((ext_vector_type(4))) short s4v;
typedef __attribute__((ext_vector_type(4))) float f4v;
typedef __attribute__((ext_vector_type(4))) unsigned int u4v;

#define MFMA32(A, B, C) __builtin_amdgcn_mfma_f32_16x16x32_bf16((A), (B), (C), 0, 0, 0)
#define MFMA16(A, B, C) __builtin_amdgcn_mfma_f32_16x16x16bf16_1k((A), (B), (C), 0, 0, 0)

static __device__ __forceinline__ unsigned short f2b(float f) {
  return __builtin_bit_cast(unsigned short, (__bf16)f);
}
static __device__ __forceinline__ float b2f(unsigned short h) {
  return __builtin_bit_cast(float, ((unsigned)h) << 16);
}

// ---- prologue: pack weights into MFMA B-fragment order (bf16) ----
// tile t: lane l holds B[k = kk*32 + (l>>4)*8 + e][n = j*16 + (l&15)], e=0..7
// bases: qkv l*24 + kk*12 + j | ow 48 + l*8 + kk*4 + j
//        ff1 64 + l*32 + kk*16 + j | ff2 128 + l*32 + kkg*4 + j
__global__ __launch_bounds__(256) void wpack(
    const float* __restrict__ qkv_w, const float* __restrict__ ow,
    const float* __restrict__ ff1_w, const float* __restrict__ ff2_w,
    unsigned int* __restrict__ ws) {
  int gid = blockIdx.x * 256 + threadIdx.x;   // 0..12287
  int tIdx = gid >> 6, lane = gid & 63;
  int ln = lane & 15, grp = lane >> 4;
  const float* src;
  if (tIdx < 48) {
    int l = tIdx / 24, r = tIdx % 24, kk = r / 12, j = r % 12;
    src = qkv_w + l * 12288 + (j * 16 + ln) * 64 + kk * 32 + grp * 8;
  } else if (tIdx < 64) {
    int u = tIdx - 48, l = u / 8, r = u % 8, kk = r / 4, j = r % 4;
    src = ow + l * 4096 + (j * 16 + ln) * 64 + kk * 32 + grp * 8;
  } else if (tIdx < 128) {
    int u = tIdx - 64, l = u / 32, r = u % 32, kk = r / 16, j = r % 16;
    src = ff1_w + l * 16384 + (j * 16 + ln) * 64 + kk * 32 + grp * 8;
  } else {
    int u = tIdx - 128, l = u / 32, r = u % 32, kk = r / 4, j = r % 4;
    src = ff2_w + l * 16384 + (j * 16 + ln) * 256 + kk * 32 + grp * 8;
  }
  unsigned p[4];
#pragma unroll
  for (int e = 0; e < 4; ++e)
    p[e] = (unsigned)f2b(src[2 * e]) | ((unsigned)f2b(src[2 * e + 1]) << 16);
  u4v val = {p[0], p[1], p[2], p[3]};
  *(u4v*)(ws + (size_t)gid * 4) = val;
}

__global__ __launch_bounds__(512) void prithvi_fused(
    const float* __restrict__ x,     const float* __restrict__ conv_w,
    const float* __restrict__ bn_g,  const float* __restrict__ bn_b,
    const float* __restrict__ bn_m,  const float* __restrict__ bn_v,
    const float* __restrict__ w_in,  const float* __restrict__ qkv_b,
    const float* __restrict__ ob,    const float* __restrict__ ln1_g,
    const float* __restrict__ ln1_b, const float* __restrict__ ff1_b,
    const float* __restrict__ ff2_b, const float* __restrict__ ln2_g,
    const float* __restrict__ ln2_b, const float* __restrict__ w_out,
    const float* __restrict__ b_out, const float* __restrict__ ws,
    float* __restrict__ out)
{
  __shared__ __align__(16) float sbuf[6144];        // 24KB: xs K-half fp32; then g bf16 (1024ch x 12)
  __shared__ __align__(16) char WBuf[8][2][7296];   // per wave, per seq-slot: HB|QB|KB (F aliases QB+KB)

  const int sp = blockIdx.x, tid = threadIdx.x;
  const int lane = tid & 63, wave = tid >> 6;

  // ---------------- conv: 2 output channels/thread, x staged in 2 K-halves ----
  {
    float acc0[12], acc1[12];
#pragma unroll
    for (int t = 0; t < 12; ++t) { acc0[t] = 0.f; acc1[t] = 0.f; }
    const float* w0p = conv_w + (size_t)tid * 1024;
    const float* w1p = conv_w + (size_t)(tid + 512) * 1024;
#pragma unroll 1
    for (int p = 0; p < 2; ++p) {
      for (int ch = tid; ch < 6144; ch += 512) {
        int e = ch / 12, t = ch - e * 12;
        sbuf[t * 512 + e] = x[(size_t)((p * 512 + e) * 12 + t) * 256 + sp];
      }
      __syncthreads();
      for (int eb = 0; eb < 512; eb += 4) {
        float4 wa = *(const float4*)(w0p + p * 512 + eb);
        float4 wb = *(const float4*)(w1p + p * 512 + eb);
#pragma unroll
        for (int t = 0; t < 12; ++t) {
          float4 xv = *(const float4*)&sbuf[t * 512 + eb];
          acc0[t] = fmaf(xv.x, wa.x, acc0[t]);
          acc0[t] = fmaf(xv.y, wa.y, acc0[t]);
          acc0[t] = fmaf(xv.z, wa.z, acc0[t]);
          acc0[t] = fmaf(xv.w, wa.w, acc0[t]);
          acc1[t] = fmaf(xv.x, wb.x, acc1[t]);
          acc1[t] = fmaf(xv.y, wb.y, acc1[t]);
          acc1[t] = fmaf(xv.z, wb.z, acc1[t]);
          acc1[t] = fmaf(xv.w, wb.w, acc1[t]);
        }
      }
      __syncthreads();
    }
    unsigned short* gW = (unsigned short*)sbuf;
    {
      float sc0 = bn_g[tid] * rsqrtf(bn_v[tid] + 1e-5f);
      float sh0 = fmaf(-bn_m[tid], sc0, bn_b[tid]);
#pragma unroll
      for (int t = 0; t < 12; ++t) {
        float z = fmaf(acc0[t], sc0, sh0);
        gW[tid * 12 + t] = f2b(0.5f * z * (1.f + erff(z * 0.70710678118654752f)));
      }
      int oc = tid + 512;
      float sc1 = bn_g[oc] * rsqrtf(bn_v[oc] + 1e-5f);
      float sh1 = fmaf(-bn_m[oc], sc1, bn_b[oc]);
#pragma unroll
      for (int t = 0; t < 12; ++t) {
        float z = fmaf(acc1[t], sc1, sh1);
        gW[oc * 12 + t] = f2b(0.5f * z * (1.f + erff(z * 0.70710678118654752f)));
      }
    }
  }
  __syncthreads();   // g (bf16, [1024][12]) read-only from here

  // ---------------- phase 3: 2 seqs in flight per wave ----------------
  const int ln = lane & 15, grp = lane >> 4;
  unsigned short* HB[2] = {(unsigned short*)&WBuf[wave][0][0],
                           (unsigned short*)&WBuf[wave][1][0]};
  unsigned short* QB[2] = {(unsigned short*)(&WBuf[wave][0][0] + 2432),
                           (unsigned short*)(&WBuf[wave][1][0] + 2432)};
  unsigned short* KB[2] = {(unsigned short*)(&WBuf[wave][0][0] + 4864),
                           (unsigned short*)(&WBuf[wave][1][0] + 4864)};
  unsigned short* FB[2] = {(unsigned short*)(&WBuf[wave][0][0] + 2432),
                           (unsigned short*)(&WBuf[wave][1][0] + 2432)};
  const unsigned short* gB = (const unsigned short*)sbuf;
  const u4v* WS = (const u4v*)ws;
#define BT(T) __builtin_bit_cast(s8v, WS[(T) * 64 + lane])

  float pe[4][4], wic[4][4];
#pragma unroll
  for (int j = 0; j < 4; ++j) {
    int d = j * 16 + ln;
    float freq = expf(-(float)(d & ~1) * (9.210340371976184f / 64.f));
#pragma unroll
    for (int i = 0; i < 4; ++i) {
      float a = freq * (float)(grp * 4 + i);
      pe[i][j] = (d & 1) ? cosf(a) : sinf(a);
    }
#pragma unroll
    for (int c = 0; c < 4; ++c) wic[j][c] = w_in[d * 4 + c];
  }
  float wo4[4];
#pragma unroll
  for (int j = 0; j < 4; ++j) wo4[j] = w_out[j * 16 + ln];
  const float bo0 = b_out[0];

#pragma unroll 1
  for (int it = 0; it < 16; ++it) {
    const int s0 = wave * 32 + it * 2;
    f4v v[2][4];

    // ---- h0 (fp32 C-frag) -> HB bf16, both seqs ----
    {
      int tb = (grp < 3) ? grp * 4 : 0;
#pragma unroll
      for (int u = 0; u < 2; ++u) {
        const int s = s0 + u;
#pragma unroll
        for (int i = 0; i < 4; ++i) {
          float g0 = b2f(gB[        s * 12 + tb + i]);
          float g1 = b2f(gB[3072 +  s * 12 + tb + i]);
          float g2 = b2f(gB[6144 +  s * 12 + tb + i]);
          float g3 = b2f(gB[9216 +  s * 12 + tb + i]);
#pragma unroll
          for (int j = 0; j < 4; ++j)
            v[u][j][i] = fmaf(g0, wic[j][0], fmaf(g1, wic[j][1],
                         fmaf(g2, wic[j][2], fmaf(g3, wic[j][3], pe[i][j]))));
        }
#pragma unroll
        for (int i = 0; i < 4; ++i)
#pragma unroll
          for (int j = 0; j < 4; ++j)
            HB[u][(grp * 4 + i) * 76 + j * 16 + ln] = f2b(v[u][j][i]);
      }
    }

#pragma unroll 1
    for (int l = 0; l < 2; ++l) {
      s4v vfrag[2][4];
      // ---- QKV: Q,K -> LDS; V -> regs (C-frag == PV B-frag) ----
      {
        s8v a0[2], a1[2];
#pragma unroll
        for (int u = 0; u < 2; ++u) {
          a0[u] = *(const s8v*)((const char*)HB[u] + ln * 152 + grp * 16);
          a1[u] = *(const s8v*)((const char*)HB[u] + ln * 152 + 64 + grp * 16);
        }
#pragma unroll
        for (int j = 0; j < 12; ++j) {
          float bb = qkv_b[l * 192 + j * 16 + ln];
#pragma unroll
          for (int u = 0; u < 2; ++u) {
            f4v c = {bb, bb, bb, bb};
            c = MFMA32(a0[u], BT(l * 24 + j), c);
            c = MFMA32(a1[u], BT(l * 24 + 12 + j), c);
            if (j < 4) {
#pragma unroll
              for (int i = 0; i < 4; ++i)
                QB[u][(grp * 4 + i) * 76 + j * 16 + ln] = f2b(c[i]);
            } else if (j < 8) {
#pragma unroll
              for (int i = 0; i < 4; ++i)
                KB[u][(grp * 4 + i) * 76 + (j - 4) * 16 + ln] = f2b(c[i]);
            } else {
              s4v pv;
              pv[0] = (short)f2b(c[0]); pv[1] = (short)f2b(c[1]);
              pv[2] = (short)f2b(c[2]); pv[3] = (short)f2b(c[3]);
              vfrag[u][j - 8] = pv;
            }
          }
        }
      }
      // ---- attention: S^T = mfma(K,Q); no max-subtract (scores finite,
      //      |s|~<4); pad k-rows (grp==3) -> e=0; P C-frag == PV A-frag ----
      {
        const f4v z4 = {0.f, 0.f, 0.f, 0.f};
#pragma unroll
        for (int hh = 0; hh < 4; ++hh) {
#pragma unroll
          for (int u = 0; u < 2; ++u) {
            s4v aK = *(const s4v*)((const char*)KB[u] + ln * 152 + hh * 32 + grp * 8);
            s4v bQ = *(const s4v*)((const char*)QB[u] + ln * 152 + hh * 32 + grp * 8);
            f4v sc = MFMA16(aK, bQ, z4);   // lane: score(q=ln, k=grp*4+i)
            float e0, e1, e2, e3;
            if (grp == 3) { e0 = e1 = e2 = e3 = 0.f; }
            else {
              e0 = __expf(sc[0] * 0.25f); e1 = __expf(sc[1] * 0.25f);
              e2 = __expf(sc[2] * 0.25f); e3 = __expf(sc[3] * 0.25f);
            }
            float sm = (e0 + e1) + (e2 + e3);
            sm += __shfl_xor(sm, 16);
            sm += __shfl_xor(sm, 32);
            float inv = 1.f / sm;
            s4v aP;
            aP[0] = (short)f2b(e0 * inv); aP[1] = (short)f2b(e1 * inv);
            aP[2] = (short)f2b(e2 * inv); aP[3] = (short)f2b(e3 * inv);
            f4v o4 = MFMA16(aP, vfrag[u][hh], z4);
#pragma unroll
            for (int i = 0; i < 4; ++i)
              KB[u][(grp * 4 + i) * 76 + hh * 16 + ln] = f2b(o4[i]);
          }
        }
      }
      // ---- O-proj + bias folded into residual v ----
      {
        s8v a0[2], a1[2];
#pragma unroll
        for (int u = 0; u < 2; ++u) {
          a0[u] = *(const s8v*)((const char*)KB[u] + ln * 152 + grp * 16);
          a1[u] = *(const s8v*)((const char*)KB[u] + ln * 152 + 64 + grp * 16);
        }
#pragma unroll
        for (int j = 0; j < 4; ++j) {
          float bb = ob[l * 64 + j * 16 + ln];
          f4v bb4 = {bb, bb, bb, bb};
#pragma unroll
          for (int u = 0; u < 2; ++u) {
            v[u][j] += bb4;
            v[u][j] = MFMA32(a0[u], BT(48 + l * 8 + j), v[u][j]);
            v[u][j] = MFMA32(a1[u], BT(48 + l * 8 + 4 + j), v[u][j]);
          }
        }
      }
      // ---- LN1 -> HB ----
      {
        const float* gp = ln1_g + l * 64;
        const float* bp = ln1_b + l * 64;
        float gg[4], bbv[4];
#pragma unroll
        for (int j = 0; j < 4; ++j) { gg[j] = gp[j * 16 + ln]; bbv[j] = bp[j * 16 + ln]; }
#pragma unroll
        for (int i = 0; i < 4; ++i) {
#pragma unroll
          for (int u = 0; u < 2; ++u) {
            float sm = v[u][0][i] + v[u][1][i] + v[u][2][i] + v[u][3][i];
            sm += __shfl_xor(sm, 1); sm += __shfl_xor(sm, 2);
            sm += __shfl_xor(sm, 4); sm += __shfl_xor(sm, 8);
            float mean = sm * 0.015625f;
            float q = 0.f;
#pragma unroll
            for (int j = 0; j < 4; ++j) { float d = v[u][j][i] - mean; q = fmaf(d, d, q); }
            q += __shfl_xor(q, 1); q += __shfl_xor(q, 2);
            q += __shfl_xor(q, 4); q += __shfl_xor(q, 8);
            float rs = rsqrtf(q * 0.015625f + 1e-5f);
#pragma unroll
            for (int j = 0; j < 4; ++j) {
              float nv = fmaf((v[u][j][i] - mean) * rs, gg[j], bbv[j]);
              v[u][j][i] = nv;
              HB[u][(grp * 4 + i) * 76 + j * 16 + ln] = f2b(nv);
            }
          }
        }
      }
      // ---- FF (F aliases QB+KB); FF2 bias + accum folded into v ----
      {
        s8v ha0[2], ha1[2];
#pragma unroll
        for (int u = 0; u < 2; ++u) {
          ha0[u] = *(const s8v*)((const char*)HB[u] + ln * 152 + grp * 16);
          ha1[u] = *(const s8v*)((const char*)HB[u] + ln * 152 + 64 + grp * 16);
        }
#pragma unroll
        for (int j = 0; j < 4; ++j) {
          float bb = ff2_b[l * 64 + j * 16 + ln];
          f4v bb4 = {bb, bb, bb, bb};
#pragma unroll
          for (int u = 0; u < 2; ++u) v[u][j] += bb4;
        }
#pragma unroll
        for (int fh = 0; fh < 2; ++fh) {
#pragma unroll
          for (int j8 = 0; j8 < 8; ++j8) {
            int jt = fh * 8 + j8;
            float bb = ff1_b[l * 256 + jt * 16 + ln];
#pragma unroll
            for (int u = 0; u < 2; ++u) {
              f4v c = {bb, bb, bb, bb};
              c = MFMA32(ha0[u], BT(64 + l * 32 + jt), c);
              c = MFMA32(ha1[u], BT(64 + l * 32 + 16 + jt), c);
#pragma unroll
              for (int i = 0; i < 4; ++i)
                FB[u][(grp * 4 + i) * 140 + j8 * 16 + ln] = f2b(fmaxf(c[i], 0.f));
            }
          }
#pragma unroll
          for (int kk2 = 0; kk2 < 4; ++kk2) {
            int kkg = fh * 4 + kk2;
#pragma unroll
            for (int u = 0; u < 2; ++u) {
              s8v fa = *(const s8v*)((const char*)FB[u] + ln * 280 + kk2 * 64 + grp * 16);
              v[u][0] = MFMA32(fa, BT(128 + l * 32 + kkg * 4 + 0), v[u][0]);
              v[u][1] = MFMA32(fa, BT(128 + l * 32 + kkg * 4 + 1), v[u][1]);
              v[u][2] = MFMA32(fa, BT(128 + l * 32 + kkg * 4 + 2), v[u][2]);
              v[u][3] = MFMA32(fa, BT(128 + l * 32 + kkg * 4 + 3), v[u][3]);
            }
          }
        }
      }
      // ---- LN2 (store HB only if another layer follows) ----
      {
        const float* gp = ln2_g + l * 64;
        const float* bp = ln2_b + l * 64;
        float gg[4], bbv[4];
#pragma unroll
        for (int j = 0; j < 4; ++j) { gg[j] = gp[j * 16 + ln]; bbv[j] = bp[j * 16 + ln]; }
#pragma unroll
        for (int i = 0; i < 4; ++i) {
#pragma unroll
          for (int u = 0; u < 2; ++u) {
            float sm = v[u][0][i] + v[u][1][i] + v[u][2][i] + v[u][3][i];
            sm += __shfl_xor(sm, 1); sm += __shfl_xor(sm, 2);
            sm += __shfl_xor(sm, 4); sm += __shfl_xor(sm, 8);
            float mean = sm * 0.015625f;
            float q = 0.f;
#pragma unroll
            for (int j = 0; j < 4; ++j) { float d = v[u][j][i] - mean; q = fmaf(d, d, q); }
            q += __shfl_xor(q, 1); q += __shfl_xor(q, 2);
            q += __shfl_xor(q, 4); q += __shfl_xor(q, 8);
            float rs = rsqrtf(q * 0.015625f + 1e-5f);
#pragma unroll
            for (int j = 0; j < 4; ++j) {
              float nv = fmaf((v[u][j][i] - mean) * rs, gg[j], bbv[j]);
              v[u][j][i] = nv;
              if (l == 0) HB[u][(grp * 4 + i) * 76 + j * 16 + ln] = f2b(nv);
            }
          }
        }
      }
    } // layer

    // ---- head: mean over t, dot w_out, sigmoid (both seqs) ----
#pragma unroll
    for (int u = 0; u < 2; ++u) {
      float cs[4];
#pragma unroll
      for (int j = 0; j < 4; ++j) {
        float c0 = (grp < 3) ? (v[u][j][0] + v[u][j][1] + v[u][j][2] + v[u][j][3]) : 0.f;
        c0 += __shfl_xor(c0, 16);
        c0 += __shfl_xor(c0, 32);
        cs[j] = c0;
      }
      float dp = cs[0] * wo4[0] + cs[1] * wo4[1] + cs[2] * wo4[2] + cs[3] * wo4[3];
      dp += __shfl_xor(dp, 1);
      dp += __shfl_xor(dp, 2);
      dp += __shfl_xor(dp, 4);
      dp += __shfl_xor(dp, 8);
      if (lane == 0) {
        const int s = s0 + u;
        float logit = dp * (1.f / 12.f) + bo0;
        int hf = ((sp >> 4) << 4) | (s >> 4);
        int wf = ((sp & 15) << 4) | (s & 15);
        out[hf * 256 + wf] = 1.f / (1.f + expf(-logit));
      }
    }
  } // seq loop
#undef BT
}

extern "C" void kernel_launch(void* const* d_in, const int* in_sizes, int n_in,
                              void* d_out, int out_size, void* d_ws, size_t ws_size,
                              hipStream_t stream) {
  (void)in_sizes; (void)n_in; (void)out_size; (void)ws_size;
  wpack<<<48, 256, 0, stream>>>(
      (const float*)d_in[7],  (const float*)d_in[9],
      (const float*)d_in[13], (const float*)d_in[15], (unsigned int*)d_ws);
  prithvi_fused<<<256, 512, 0, stream>>>(
      (const float*)d_in[0],  (const float*)d_in[1],  (const float*)d_in[2],
      (const float*)d_in[3],  (const float*)d_in[4],  (const float*)d_in[5],
      (const float*)d_in[6],  (const float*)d_in[8],  (const float*)d_in[10],
      (const float*)d_in[11], (const float*)d_in[12], (const float*)d_in[14],
      (const float*)d_in[16], (const float*)d_in[17], (const float*)d_in[18],
      (const float*)d_in[19], (const float*)d_in[20], (const float*)d_ws,
      (float*)d_out);
}